// Round 1
// baseline (2911.159 us; speedup 1.0000x reference)
//
#include <hip/hip_runtime.h>
#include <hip/hip_bf16.h>

// Problem constants
#define B   32
#define NQ  1024
#define GS  1024
#define E   128
#define NH  8
#define HD  16

#define NEGF (-1.0e30f)

// ---------------------------------------------------------------------------
// Generic 128-wide GEMM: out[row][c] = sum_k A[row][k] * Wt[c][k]
// MODE 0: W is per-head [8][128][16] (Wq/Wk/Wv) -> col c = h*16+e, k = d
// MODE 1: W is plain [128][128] row-major (contraction-major) -> Wt[c][k]=W[k][c]
// Block: 256 threads; tile 128 rows x 128 cols; K tiled by 32.
// Thread (cg = t&15, rg = t>>4) owns rows rg+16i (i<8), cols cg+16j (j<8).
// ---------------------------------------------------------------------------
template <int MODE>
__device__ __forceinline__ void gemm_body(const float* __restrict__ A,
                                          const float* __restrict__ W,
                                          float* __restrict__ out, int row0) {
    __shared__ float As[128 * 36];   // stride 36: b128-aligned, bank-safe
    __shared__ float Wt[128 * 36];

    const int t  = threadIdx.x;
    const int cg = t & 15;
    const int rg = t >> 4;

    float acc[8][8];
#pragma unroll
    for (int i = 0; i < 8; ++i)
#pragma unroll
        for (int j = 0; j < 8; ++j) acc[i][j] = 0.0f;

    const float4* A4 = (const float4*)A;

    for (int kt = 0; kt < 4; ++kt) {
        __syncthreads();
        // --- stage A tile: rows row0..row0+127, k = kt*32..+31
#pragma unroll
        for (int i = 0; i < 4; ++i) {
            int f   = t + i * 256;        // 0..1023 float4 units
            int row = f >> 3;
            int kq  = f & 7;
            float4 v = A4[(size_t)(row0 + row) * 32 + kt * 8 + kq];
            *(float4*)&As[row * 36 + kq * 4] = v;
        }
        // --- stage W tile transposed: Wt[c][kl], kl = 0..31
#pragma unroll
        for (int i = 0; i < 4; ++i) {
            int g = t + i * 256;          // 0..1023 float4 units
            if (MODE == 0) {
                int hh = g >> 7;          // head
                int dl = (g >> 2) & 31;   // local k
                int e4 = g & 3;           // e quarter
                float4 w = *(const float4*)&W[hh * 2048 + (kt * 32 + dl) * 16 + e4 * 4];
                int c0 = hh * 16 + e4 * 4;
                Wt[(c0 + 0) * 36 + dl] = w.x;
                Wt[(c0 + 1) * 36 + dl] = w.y;
                Wt[(c0 + 2) * 36 + dl] = w.z;
                Wt[(c0 + 3) * 36 + dl] = w.w;
            } else {
                int cl = g >> 5;          // local contraction row
                int j4 = g & 31;          // out-col quarter
                float4 w = *(const float4*)&W[(size_t)(kt * 32 + cl) * 128 + j4 * 4];
                Wt[(j4 * 4 + 0) * 36 + cl] = w.x;
                Wt[(j4 * 4 + 1) * 36 + cl] = w.y;
                Wt[(j4 * 4 + 2) * 36 + cl] = w.z;
                Wt[(j4 * 4 + 3) * 36 + cl] = w.w;
            }
        }
        __syncthreads();
        // --- compute
#pragma unroll
        for (int k4 = 0; k4 < 8; ++k4) {
            float4 a[8], bb[8];
#pragma unroll
            for (int i = 0; i < 8; ++i)
                a[i] = *(const float4*)&As[(rg + 16 * i) * 36 + k4 * 4];
#pragma unroll
            for (int j = 0; j < 8; ++j)
                bb[j] = *(const float4*)&Wt[(cg + 16 * j) * 36 + k4 * 4];
#pragma unroll
            for (int i = 0; i < 8; ++i)
#pragma unroll
                for (int j = 0; j < 8; ++j) {
                    acc[i][j] += a[i].x * bb[j].x;
                    acc[i][j] += a[i].y * bb[j].y;
                    acc[i][j] += a[i].z * bb[j].z;
                    acc[i][j] += a[i].w * bb[j].w;
                }
        }
    }
#pragma unroll
    for (int i = 0; i < 8; ++i)
#pragma unroll
        for (int j = 0; j < 8; ++j)
            out[(size_t)(row0 + rg + 16 * i) * 128 + cg + 16 * j] = acc[i][j];
}

__global__ __launch_bounds__(256) void proj_kernel(const float* __restrict__ q,
                                                   const float* __restrict__ h,
                                                   const float* __restrict__ Wq,
                                                   const float* __restrict__ Wk,
                                                   const float* __restrict__ Wv,
                                                   float* __restrict__ Qw,
                                                   float* __restrict__ Kw,
                                                   float* __restrict__ Vw) {
    int row0 = blockIdx.x * 128;
    if (blockIdx.y == 0)      gemm_body<0>(q, Wq, Qw, row0);
    else if (blockIdx.y == 1) gemm_body<0>(h, Wk, Kw, row0);
    else                      gemm_body<0>(h, Wv, Vw, row0);
}

__global__ __launch_bounds__(256) void outproj_kernel(const float* __restrict__ heads,
                                                      const float* __restrict__ Wout,
                                                      float* __restrict__ out) {
    gemm_body<1>(heads, Wout, out, blockIdx.x * 128);
}

// ---------------------------------------------------------------------------
// Flash attention, fp32, online softmax in exp2 domain.
// Block: 128 threads = 8 heads (h = t>>4) x 16 row-groups (rg = t&15).
// Each thread: 4 q-rows (rg + 16i) of one head; q-tile = 64 rows.
// K/V staged in LDS in 32-key tiles; softmax processed in 8-key subtiles.
// Grid (b, qt): consecutive block ids vary b -> same-batch tiles share an XCD.
// ---------------------------------------------------------------------------
__global__ __launch_bounds__(128, 2) void flash_kernel(const float* __restrict__ Q,
                                                       const float* __restrict__ K,
                                                       const float* __restrict__ V,
                                                       const int* __restrict__ mask,
                                                       float* __restrict__ heads) {
    __shared__ float Kt[32 * 128];
    __shared__ float Vt[32 * 128];

    const int b  = blockIdx.x;
    const int q0 = blockIdx.y * 64;
    const int t  = threadIdx.x;
    const int hh = t >> 4;   // head
    const int rg = t & 15;   // row group

    const float SC = 0.25f * 1.4426950408889634f;  // 1/sqrt(16) * log2(e)

    float Qr[4][16], O[4][16], m[4], l[4];
#pragma unroll
    for (int i = 0; i < 4; ++i) {
        const float4* qp =
            (const float4*)&Q[((size_t)b * NQ + q0 + rg + 16 * i) * 128 + hh * 16];
#pragma unroll
        for (int c = 0; c < 4; ++c) {
            float4 v = qp[c];
            Qr[i][4 * c + 0] = v.x * SC;
            Qr[i][4 * c + 1] = v.y * SC;
            Qr[i][4 * c + 2] = v.z * SC;
            Qr[i][4 * c + 3] = v.w * SC;
        }
        m[i] = NEGF;
        l[i] = 0.0f;
#pragma unroll
        for (int e = 0; e < 16; ++e) O[i][e] = 0.0f;
    }

    float4* Kt4 = (float4*)Kt;
    float4* Vt4 = (float4*)Vt;

    for (int g0 = 0; g0 < GS; g0 += 32) {
        __syncthreads();
        const float4* K4 = (const float4*)&K[((size_t)b * GS + g0) * 128];
        const float4* V4 = (const float4*)&V[((size_t)b * GS + g0) * 128];
#pragma unroll
        for (int j = 0; j < 8; ++j) {
            int f = t + j * 128;
            Kt4[f] = K4[f];
            Vt4[f] = V4[f];
        }
        __syncthreads();

#pragma unroll
        for (int sub = 0; sub < 4; ++sub) {
            float p[4][8];
            // ---- scores: p[i][gg] = Qr[i] . K[gl]  (already in exp2 domain)
#pragma unroll
            for (int gg = 0; gg < 8; ++gg) {
                int gl = sub * 8 + gg;
                const float4* kp = (const float4*)&Kt[gl * 128 + hh * 16];
                float4 k0 = kp[0], k1 = kp[1], k2 = kp[2], k3 = kp[3];
#pragma unroll
                for (int i = 0; i < 4; ++i) {
                    float s = Qr[i][0] * k0.x;
                    s += Qr[i][1] * k0.y;  s += Qr[i][2] * k0.z;  s += Qr[i][3] * k0.w;
                    s += Qr[i][4] * k1.x;  s += Qr[i][5] * k1.y;  s += Qr[i][6] * k1.z;
                    s += Qr[i][7] * k1.w;  s += Qr[i][8] * k2.x;  s += Qr[i][9] * k2.y;
                    s += Qr[i][10] * k2.z; s += Qr[i][11] * k2.w; s += Qr[i][12] * k3.x;
                    s += Qr[i][13] * k3.y; s += Qr[i][14] * k3.z; s += Qr[i][15] * k3.w;
                    p[i][gg] = s;
                }
            }
            // ---- mask + online softmax state update
#pragma unroll
            for (int i = 0; i < 4; ++i) {
                const int4* mp = (const int4*)&mask[((size_t)b * NQ + q0 + rg + 16 * i) * GS +
                                                    g0 + sub * 8];
                int4 ma = mp[0], mb = mp[1];
                int mm[8] = {ma.x, ma.y, ma.z, ma.w, mb.x, mb.y, mb.z, mb.w};
#pragma unroll
                for (int gg = 0; gg < 8; ++gg)
                    if (mm[gg] != 0) p[i][gg] = NEGF;

                float mx = m[i];
#pragma unroll
                for (int gg = 0; gg < 8; ++gg) mx = fmaxf(mx, p[i][gg]);
                float alpha = exp2f(m[i] - mx);   // mx==NEGF -> exp2(0)=1, harmless
                m[i] = mx;
                float ps = 0.0f;
#pragma unroll
                for (int gg = 0; gg < 8; ++gg) {
                    float pe = (p[i][gg] == NEGF) ? 0.0f : exp2f(p[i][gg] - mx);
                    p[i][gg] = pe;
                    ps += pe;
                }
                l[i] = l[i] * alpha + ps;
#pragma unroll
                for (int e = 0; e < 16; ++e) O[i][e] *= alpha;
            }
            // ---- PV accumulate
#pragma unroll
            for (int gg = 0; gg < 8; ++gg) {
                int gl = sub * 8 + gg;
                const float4* vp = (const float4*)&Vt[gl * 128 + hh * 16];
                float4 v0 = vp[0], v1 = vp[1], v2 = vp[2], v3 = vp[3];
#pragma unroll
                for (int i = 0; i < 4; ++i) {
                    float pe = p[i][gg];
                    O[i][0]  += pe * v0.x;  O[i][1]  += pe * v0.y;
                    O[i][2]  += pe * v0.z;  O[i][3]  += pe * v0.w;
                    O[i][4]  += pe * v1.x;  O[i][5]  += pe * v1.y;
                    O[i][6]  += pe * v1.z;  O[i][7]  += pe * v1.w;
                    O[i][8]  += pe * v2.x;  O[i][9]  += pe * v2.y;
                    O[i][10] += pe * v2.z;  O[i][11] += pe * v2.w;
                    O[i][12] += pe * v3.x;  O[i][13] += pe * v3.y;
                    O[i][14] += pe * v3.z;  O[i][15] += pe * v3.w;
                }
            }
        }
    }

#pragma unroll
    for (int i = 0; i < 4; ++i) {
        float rl = (l[i] > 0.0f) ? 1.0f / l[i] : 0.0f;
        float4* op = (float4*)&heads[((size_t)b * NQ + q0 + rg + 16 * i) * 128 + hh * 16];
        op[0] = make_float4(O[i][0] * rl, O[i][1] * rl, O[i][2] * rl, O[i][3] * rl);
        op[1] = make_float4(O[i][4] * rl, O[i][5] * rl, O[i][6] * rl, O[i][7] * rl);
        op[2] = make_float4(O[i][8] * rl, O[i][9] * rl, O[i][10] * rl, O[i][11] * rl);
        op[3] = make_float4(O[i][12] * rl, O[i][13] * rl, O[i][14] * rl, O[i][15] * rl);
    }
}

extern "C" void kernel_launch(void* const* d_in, const int* in_sizes, int n_in,
                              void* d_out, int out_size, void* d_ws, size_t ws_size,
                              hipStream_t stream) {
    const float* q    = (const float*)d_in[0];
    const float* h    = (const float*)d_in[1];
    const int*   mask = (const int*)d_in[2];   // bool -> int32 per harness rule
    const float* Wq   = (const float*)d_in[3];
    const float* Wk   = (const float*)d_in[4];
    const float* Wv   = (const float*)d_in[5];
    const float* Wout = (const float*)d_in[6];
    float* out = (float*)d_out;

    const size_t NTOK = (size_t)B * NQ;        // 32768
    float* Qw = (float*)d_ws;                  // [32768][128]
    float* Kw = Qw + NTOK * 128;
    float* Vw = Kw + NTOK * 128;
    float* Hw = Vw + NTOK * 128;               // heads, [32768][128]

    // 1) Q/K/V projections: 3 x (32768 x 128 @ 128 x 128)
    proj_kernel<<<dim3(256, 3), 256, 0, stream>>>(q, h, Wq, Wk, Wv, Qw, Kw, Vw);
    // 2) fused masked attention -> heads
    flash_kernel<<<dim3(B, NQ / 64), 128, 0, stream>>>(Qw, Kw, Vw, mask, Hw);
    // 3) output projection
    outproj_kernel<<<dim3(256, 1), 256, 0, stream>>>(Hw, Wout, out);
}

// Round 2
// 560.660 us; speedup vs baseline: 5.1924x; 5.1924x over previous
//
#include <hip/hip_runtime.h>

typedef unsigned short u16;
typedef unsigned int   u32;
typedef short bf16x8 __attribute__((ext_vector_type(8)));
typedef float f32x4  __attribute__((ext_vector_type(4)));

#define NB  32
#define NQ  1024
#define GS  1024
#define NH  8
#define NEGF (-1.0e30f)
#define SCQ (0.25f * 1.4426950408889634f)   /* 1/sqrt(16) * log2(e) */

#define MFMA16(a, b, c) __builtin_amdgcn_mfma_f32_16x16x32_bf16(a, b, c, 0, 0, 0)

__device__ __forceinline__ u16 f2bf(float f) {  // RNE float->bf16 bits
    u32 u = __float_as_uint(f);
    return (u16)((u + 0x7fffu + ((u >> 16) & 1u)) >> 16);
}

// ---------------------------------------------------------------------------
// 128-wide fp32 GEMM (unchanged math). MODE 0: W=[8][128][16] per-head;
// MODE 1: W=[128][128]. OUTB 1: write bf16 bits * scale, else fp32.
// ---------------------------------------------------------------------------
template <int MODE, int OUTB>
__device__ __forceinline__ void gemm_body(const float* __restrict__ A,
                                          const float* __restrict__ W,
                                          float* __restrict__ outf,
                                          u16* __restrict__ outb,
                                          float scale, int row0) {
    __shared__ float As[128 * 36];
    __shared__ float Wt[128 * 36];

    const int t  = threadIdx.x;
    const int cg = t & 15;
    const int rg = t >> 4;

    float acc[8][8];
#pragma unroll
    for (int i = 0; i < 8; ++i)
#pragma unroll
        for (int j = 0; j < 8; ++j) acc[i][j] = 0.0f;

    const float4* A4 = (const float4*)A;

    for (int kt = 0; kt < 4; ++kt) {
        __syncthreads();
#pragma unroll
        for (int i = 0; i < 4; ++i) {
            int f   = t + i * 256;
            int row = f >> 3;
            int kq  = f & 7;
            float4 v = A4[(size_t)(row0 + row) * 32 + kt * 8 + kq];
            *(float4*)&As[row * 36 + kq * 4] = v;
        }
#pragma unroll
        for (int i = 0; i < 4; ++i) {
            int g = t + i * 256;
            if (MODE == 0) {
                int hh = g >> 7;
                int dl = (g >> 2) & 31;
                int e4 = g & 3;
                float4 w = *(const float4*)&W[hh * 2048 + (kt * 32 + dl) * 16 + e4 * 4];
                int c0 = hh * 16 + e4 * 4;
                Wt[(c0 + 0) * 36 + dl] = w.x;
                Wt[(c0 + 1) * 36 + dl] = w.y;
                Wt[(c0 + 2) * 36 + dl] = w.z;
                Wt[(c0 + 3) * 36 + dl] = w.w;
            } else {
                int cl = g >> 5;
                int j4 = g & 31;
                float4 w = *(const float4*)&W[(size_t)(kt * 32 + cl) * 128 + j4 * 4];
                Wt[(j4 * 4 + 0) * 36 + cl] = w.x;
                Wt[(j4 * 4 + 1) * 36 + cl] = w.y;
                Wt[(j4 * 4 + 2) * 36 + cl] = w.z;
                Wt[(j4 * 4 + 3) * 36 + cl] = w.w;
            }
        }
        __syncthreads();
#pragma unroll
        for (int k4 = 0; k4 < 8; ++k4) {
            float4 a[8], bb[8];
#pragma unroll
            for (int i = 0; i < 8; ++i)
                a[i] = *(const float4*)&As[(rg + 16 * i) * 36 + k4 * 4];
#pragma unroll
            for (int j = 0; j < 8; ++j)
                bb[j] = *(const float4*)&Wt[(cg + 16 * j) * 36 + k4 * 4];
#pragma unroll
            for (int i = 0; i < 8; ++i)
#pragma unroll
                for (int j = 0; j < 8; ++j) {
                    acc[i][j] += a[i].x * bb[j].x;
                    acc[i][j] += a[i].y * bb[j].y;
                    acc[i][j] += a[i].z * bb[j].z;
                    acc[i][j] += a[i].w * bb[j].w;
                }
        }
    }
#pragma unroll
    for (int i = 0; i < 8; ++i)
#pragma unroll
        for (int j = 0; j < 8; ++j) {
            size_t idx = (size_t)(row0 + rg + 16 * i) * 128 + cg + 16 * j;
            if (OUTB) outb[idx] = f2bf(acc[i][j] * scale);
            else      outf[idx] = acc[i][j];
        }
}

__global__ __launch_bounds__(256) void proj_kernel(const float* __restrict__ q,
                                                   const float* __restrict__ h,
                                                   const float* __restrict__ Wq,
                                                   const float* __restrict__ Wk,
                                                   const float* __restrict__ Wv,
                                                   u16* __restrict__ Qb,
                                                   u16* __restrict__ Kb,
                                                   u16* __restrict__ Vb) {
    int row0 = blockIdx.x * 128;
    if (blockIdx.y == 0)      gemm_body<0, 1>(q, Wq, nullptr, Qb, SCQ, row0);
    else if (blockIdx.y == 1) gemm_body<0, 1>(h, Wk, nullptr, Kb, 1.0f, row0);
    else                      gemm_body<0, 1>(h, Wv, nullptr, Vb, 1.0f, row0);
}

__global__ __launch_bounds__(256) void outproj_kernel(const float* __restrict__ heads,
                                                      const float* __restrict__ Wout,
                                                      float* __restrict__ out) {
    gemm_body<1, 0>(heads, Wout, out, nullptr, 1.0f, blockIdx.x * 128);
}

// ---------------------------------------------------------------------------
// MFMA flash attention. Block = (batch, 32 q-rows), 512 thr = 8 waves = 8 heads.
// Scores: zero-padded 16x16x32 bf16 MFMA (HD=16). C/D layout col=lane&15,
// row=quad*4+reg (verified m89). P -> bf16 -> per-wave LDS -> A-frag for PV.
// LDS strides padded (136/40) so b128 frag reads are <=2-way bank aliased.
// ---------------------------------------------------------------------------
__global__ __launch_bounds__(512, 4) void flash_mfma(const u16* __restrict__ Qb,
                                                     const u16* __restrict__ Kb,
                                                     const u16* __restrict__ Vb,
                                                     const int* __restrict__ mask,
                                                     float* __restrict__ heads) {
    __shared__ u16 Kt[32 * 136];       // [key][dim], stride 136
    __shared__ u16 Vtt[128 * 40];      // [dim][key], stride 40 (transposed)
    __shared__ u16 Ps[NH][32 * 40];    // per-wave P scratch [row][key], stride 40

    const int b    = blockIdx.x;
    const int q0   = blockIdx.y * 32;
    const int t    = threadIdx.x;
    const int hh   = t >> 6;
    const int lane = t & 63;
    const int quad = lane >> 4;
    const int c    = lane & 15;

    const f32x4  zf = {0.f, 0.f, 0.f, 0.f};
    const bf16x8 zb = {0, 0, 0, 0, 0, 0, 0, 0};

    // Q A-frags: A[m=c][k=quad*8+j], real k<16 -> quads 2,3 zero.
    bf16x8 qf[2];
#pragma unroll
    for (int s = 0; s < 2; ++s) {
        qf[s] = zb;
        if (quad < 2)
            qf[s] = *(const bf16x8*)&Qb[((size_t)b * NQ + q0 + s * 16 + c) * 128 +
                                        hh * 16 + quad * 8];
    }

    f32x4 O[2] = {zf, zf};
    float mrow[2][4], lrow[2][4];
#pragma unroll
    for (int s = 0; s < 2; ++s)
#pragma unroll
        for (int r = 0; r < 4; ++r) { mrow[s][r] = NEGF; lrow[s][r] = 0.f; }

    const int skey = t >> 4;            // K staging: key 0..31
    const int sd0  = (t & 15) * 8;      //            dim octet
    const int vkey = t & 31;            // V staging: key 0..31
    const int vd0  = (t >> 5) * 8;      //            dim octet

    for (int g0 = 0; g0 < GS; g0 += 32) {
        __syncthreads();
        // stage K [32][128] -> Kt[key][dim] (coalesced), V -> Vtt[dim][key]
        *(int4*)&Kt[skey * 136 + sd0] =
            *(const int4*)&Kb[((size_t)b * GS + g0 + skey) * 128 + sd0];
        {
            union { int4 v; u16 s[8]; } wv;
            wv.v = *(const int4*)&Vb[((size_t)b * GS + g0 + vkey) * 128 + vd0];
#pragma unroll
            for (int j = 0; j < 8; ++j) Vtt[(vd0 + j) * 40 + vkey] = wv.s[j];
        }
        __syncthreads();

        // mask: mk[s][r][kt] = mask[b][q0+s*16+quad*4+r][g0+kt*16+c]
        int mk[2][4][2];
#pragma unroll
        for (int s = 0; s < 2; ++s)
#pragma unroll
            for (int r = 0; r < 4; ++r) {
                const int* mp = &mask[((size_t)b * NQ + q0 + s * 16 + quad * 4 + r) * GS +
                                      g0 + c];
                mk[s][r][0] = mp[0];
                mk[s][r][1] = mp[16];
            }

        // scores: 2 row-subtiles x 2 key-subtiles
        f32x4 sc[2][2];
#pragma unroll
        for (int kt = 0; kt < 2; ++kt) {
            bf16x8 kf = zb;  // B[k=dim=quad*8+j][n=key=c]; dims>=16 zero
            if (quad < 2)
                kf = *(const bf16x8*)&Kt[(kt * 16 + c) * 136 + hh * 16 + quad * 8];
            sc[0][kt] = MFMA16(qf[0], kf, zf);
            sc[1][kt] = MFMA16(qf[1], kf, zf);
        }
        // V B-frag: B[k=key=quad*8+j][n=e=c]
        bf16x8 vf = *(const bf16x8*)&Vtt[(hh * 16 + c) * 40 + quad * 8];

        // online softmax (exp2 domain; Q pre-scaled)
#pragma unroll
        for (int s = 0; s < 2; ++s) {
#pragma unroll
            for (int r = 0; r < 4; ++r) {
                float x0 = mk[s][r][0] ? NEGF : sc[s][0][r];
                float x1 = mk[s][r][1] ? NEGF : sc[s][1][r];
                float mx = fmaxf(x0, x1);
                mx = fmaxf(mx, __shfl_xor(mx, 1));
                mx = fmaxf(mx, __shfl_xor(mx, 2));
                mx = fmaxf(mx, __shfl_xor(mx, 4));
                mx = fmaxf(mx, __shfl_xor(mx, 8));
                float mn = fmaxf(mrow[s][r], mx);
                float alpha = exp2f(mrow[s][r] - mn);   // NEGF-NEGF=0 -> 1
                mrow[s][r] = mn;
                float p0 = (x0 <= -1e29f) ? 0.f : exp2f(x0 - mn);
                float p1 = (x1 <= -1e29f) ? 0.f : exp2f(x1 - mn);
                float rs = p0 + p1;
                rs += __shfl_xor(rs, 1);
                rs += __shfl_xor(rs, 2);
                rs += __shfl_xor(rs, 4);
                rs += __shfl_xor(rs, 8);
                lrow[s][r] = lrow[s][r] * alpha + rs;
                O[s][r] *= alpha;
                int prow = s * 16 + quad * 4 + r;       // C-layout row
                Ps[hh][prow * 40 + c]      = f2bf(p0);  // key col kt*16+c
                Ps[hh][prow * 40 + 16 + c] = f2bf(p1);
            }
        }

        // PV: A=P[m=row=c][k=key=quad*8+j] (same-wave LDS RAW, no barrier)
#pragma unroll
        for (int s = 0; s < 2; ++s) {
            bf16x8 pf = *(const bf16x8*)&Ps[hh][(s * 16 + c) * 40 + quad * 8];
            O[s] = MFMA16(pf, vf, O[s]);
        }
    }

    // epilogue: heads[b][q0+s*16+quad*4+r][hh*16+c] = O/l
#pragma unroll
    for (int s = 0; s < 2; ++s)
#pragma unroll
        for (int r = 0; r < 4; ++r) {
            float l  = lrow[s][r];
            float rl = (l > 0.f) ? 1.f / l : 0.f;
            heads[((size_t)b * NQ + q0 + s * 16 + quad * 4 + r) * 128 + hh * 16 + c] =
                O[s][r] * rl;
        }
}

extern "C" void kernel_launch(void* const* d_in, const int* in_sizes, int n_in,
                              void* d_out, int out_size, void* d_ws, size_t ws_size,
                              hipStream_t stream) {
    const float* q    = (const float*)d_in[0];
    const float* h    = (const float*)d_in[1];
    const int*   mask = (const int*)d_in[2];
    const float* Wq   = (const float*)d_in[3];
    const float* Wk   = (const float*)d_in[4];
    const float* Wv   = (const float*)d_in[5];
    const float* Wout = (const float*)d_in[6];
    float* out = (float*)d_out;

    const size_t NTOK = (size_t)NB * NQ;   // 32768
    u16* Qb = (u16*)d_ws;                  // 8 MB each
    u16* Kb = Qb + NTOK * 128;
    u16* Vb = Kb + NTOK * 128;
    float* Hw = (float*)(Vb + NTOK * 128); // heads fp32, 16 MB

    proj_kernel<<<dim3(256, 3), 256, 0, stream>>>(q, h, Wq, Wk, Wv, Qb, Kb, Vb);
    flash_mfma<<<dim3(NB, NQ / 32), 512, 0, stream>>>(Qb, Kb, Vb, mask, Hw);
    outproj_kernel<<<dim3(256, 1), 256, 0, stream>>>(Hw, Wout, out);
}

// Round 3
// 419.313 us; speedup vs baseline: 6.9427x; 1.3371x over previous
//
#include <hip/hip_runtime.h>

typedef unsigned short u16;
typedef unsigned int   u32;
typedef short bf16x8 __attribute__((ext_vector_type(8)));
typedef float f32x4  __attribute__((ext_vector_type(4)));

#define NB  32
#define NQ  1024
#define GS  1024
#define NH  8
#define SCQ (0.25f * 1.4426950408889634f)   /* 1/sqrt(16) * log2(e) */

#define MFMA16(a, b, c) __builtin_amdgcn_mfma_f32_16x16x32_bf16(a, b, c, 0, 0, 0)

__device__ __forceinline__ u16 f2bf(float f) {  // RNE float->bf16 bits (epilogue only)
    u32 u = __float_as_uint(f);
    return (u16)((u + 0x7fffu + ((u >> 16) & 1u)) >> 16);
}

// ---------------------------------------------------------------------------
// 128-wide fp32 GEMM. MODE 0: W=[8][128][16] per-head -> bf16 row-major out.
// MODE 1: W=[128][128] -> fp32 row-major out.
// MODE 2: W=[8][128][16] per-head -> bf16 out TRANSPOSED per batch:
//         Vt_g[b][dim][token]  (dim=128, token=1024 per batch)
// ---------------------------------------------------------------------------
template <int MODE>
__device__ __forceinline__ void gemm_body(const float* __restrict__ A,
                                          const float* __restrict__ W,
                                          float* __restrict__ outf,
                                          u16* __restrict__ outb,
                                          float scale, int row0) {
    __shared__ float As[128 * 36];
    __shared__ float Wt[128 * 36];

    const int t  = threadIdx.x;
    const int cg = t & 15;
    const int rg = t >> 4;

    float acc[8][8];
#pragma unroll
    for (int i = 0; i < 8; ++i)
#pragma unroll
        for (int j = 0; j < 8; ++j) acc[i][j] = 0.0f;

    const float4* A4 = (const float4*)A;

    for (int kt = 0; kt < 4; ++kt) {
        __syncthreads();
#pragma unroll
        for (int i = 0; i < 4; ++i) {
            int f   = t + i * 256;
            int row = f >> 3;
            int kq  = f & 7;
            float4 v = A4[(size_t)(row0 + row) * 32 + kt * 8 + kq];
            *(float4*)&As[row * 36 + kq * 4] = v;
        }
#pragma unroll
        for (int i = 0; i < 4; ++i) {
            int g = t + i * 256;
            if (MODE != 1) {
                int hh = g >> 7;
                int dl = (g >> 2) & 31;
                int e4 = g & 3;
                float4 w = *(const float4*)&W[hh * 2048 + (kt * 32 + dl) * 16 + e4 * 4];
                int c0 = hh * 16 + e4 * 4;
                Wt[(c0 + 0) * 36 + dl] = w.x;
                Wt[(c0 + 1) * 36 + dl] = w.y;
                Wt[(c0 + 2) * 36 + dl] = w.z;
                Wt[(c0 + 3) * 36 + dl] = w.w;
            } else {
                int cl = g >> 5;
                int j4 = g & 31;
                float4 w = *(const float4*)&W[(size_t)(kt * 32 + cl) * 128 + j4 * 4];
                Wt[(j4 * 4 + 0) * 36 + cl] = w.x;
                Wt[(j4 * 4 + 1) * 36 + cl] = w.y;
                Wt[(j4 * 4 + 2) * 36 + cl] = w.z;
                Wt[(j4 * 4 + 3) * 36 + cl] = w.w;
            }
        }
        __syncthreads();
#pragma unroll
        for (int k4 = 0; k4 < 8; ++k4) {
            float4 a[8], bb[8];
#pragma unroll
            for (int i = 0; i < 8; ++i)
                a[i] = *(const float4*)&As[(rg + 16 * i) * 36 + k4 * 4];
#pragma unroll
            for (int j = 0; j < 8; ++j)
                bb[j] = *(const float4*)&Wt[(cg + 16 * j) * 36 + k4 * 4];
#pragma unroll
            for (int i = 0; i < 8; ++i)
#pragma unroll
                for (int j = 0; j < 8; ++j) {
                    acc[i][j] += a[i].x * bb[j].x;
                    acc[i][j] += a[i].y * bb[j].y;
                    acc[i][j] += a[i].z * bb[j].z;
                    acc[i][j] += a[i].w * bb[j].w;
                }
        }
    }
#pragma unroll
    for (int i = 0; i < 8; ++i)
#pragma unroll
        for (int j = 0; j < 8; ++j) {
            int row = row0 + rg + 16 * i;
            int col = cg + 16 * j;
            if (MODE == 2) {
                int b  = row >> 10;
                int tb = row & 1023;
                outb[(size_t)b * (128 * 1024) + (size_t)col * 1024 + tb] =
                    f2bf(acc[i][j] * scale);
            } else if (MODE == 0) {
                outb[(size_t)row * 128 + col] = f2bf(acc[i][j] * scale);
            } else {
                outf[(size_t)row * 128 + col] = acc[i][j];
            }
        }
}

__global__ __launch_bounds__(256) void proj_kernel(const float* __restrict__ q,
                                                   const float* __restrict__ h,
                                                   const float* __restrict__ Wq,
                                                   const float* __restrict__ Wk,
                                                   const float* __restrict__ Wv,
                                                   u16* __restrict__ Qb,
                                                   u16* __restrict__ Kb,
                                                   u16* __restrict__ Vtg) {
    int row0 = blockIdx.x * 128;
    if (blockIdx.y == 0)      gemm_body<0>(q, Wq, nullptr, Qb, SCQ, row0);
    else if (blockIdx.y == 1) gemm_body<0>(h, Wk, nullptr, Kb, 1.0f, row0);
    else                      gemm_body<2>(h, Wv, nullptr, Vtg, 1.0f, row0);
}

__global__ __launch_bounds__(256) void outproj_kernel(const float* __restrict__ heads,
                                                      const float* __restrict__ Wout,
                                                      float* __restrict__ out) {
    gemm_body<1>(heads, Wout, out, nullptr, 1.0f, blockIdx.x * 128);
}

// ---------------------------------------------------------------------------
// MFMA flash attention, max-free softmax (scores bounded; exp2 domain).
// Block = (batch, 32 q-rows), 512 thr = 8 waves = 8 heads.
// 16x16x32 bf16 MFMA throughout (verified layouts). P round-trips LDS
// per-wave; l accumulated as per-lane partials, reduced once at the end.
// Next K/V tile prefetched into registers during compute.
// ---------------------------------------------------------------------------
__global__ __launch_bounds__(512, 4) void flash_mfma(const u16* __restrict__ Qb,
                                                     const u16* __restrict__ Kb,
                                                     const u16* __restrict__ Vtg,
                                                     const int* __restrict__ mask,
                                                     float* __restrict__ heads) {
    __shared__ u16 Kt[32 * 136];        // [key][dim], stride 136
    __shared__ u16 Vtt[128 * 36];       // [dim][key], stride 36
    __shared__ u16 Ps[NH][32 * 34];     // per-wave P [row][key], stride 34

    const int b    = blockIdx.x;
    const int q0   = blockIdx.y * 32;
    const int t    = threadIdx.x;
    const int hh   = t >> 6;
    const int lane = t & 63;
    const int quad = lane >> 4;
    const int c    = lane & 15;

    const f32x4  zf = {0.f, 0.f, 0.f, 0.f};
    const bf16x8 zb = {0, 0, 0, 0, 0, 0, 0, 0};

    // Q A-frags: A[m=c][k=quad*8+j], real k<16 -> quads 2,3 zero.
    bf16x8 qf[2];
#pragma unroll
    for (int s = 0; s < 2; ++s) {
        qf[s] = zb;
        if (quad < 2)
            qf[s] = *(const bf16x8*)&Qb[((size_t)b * NQ + q0 + s * 16 + c) * 128 +
                                        hh * 16 + quad * 8];
    }

    f32x4 O[2] = {zf, zf};
    float ls[2][4] = {{0.f, 0.f, 0.f, 0.f}, {0.f, 0.f, 0.f, 0.f}};

    // staging indices
    const int skey = t >> 4;            // K: key 0..31, dim octet (t&15)*8
    const int sd0  = (t & 15) * 8;
    const int vdim = t >> 2;            // V: dim 0..127, key octet (t&3)*8
    const int vk0  = (t & 3) * 8;

    const u16* Kbase = &Kb[((size_t)b * GS + skey) * 128 + sd0];
    const u16* Vbase = &Vtg[(size_t)b * (128 * 1024) + (size_t)vdim * 1024 + vk0];
    const int* mb    = mask + ((size_t)b * NQ + q0 + quad * 4) * GS + c;

    int4 kreg = *(const int4*)Kbase;
    int4 vreg = *(const int4*)Vbase;

    for (int g0 = 0; g0 < GS; g0 += 32) {
        __syncthreads();
        *(int4*)&Kt[skey * 136 + sd0] = kreg;
        *(int4*)&Vtt[vdim * 36 + vk0] = vreg;
        __syncthreads();

        if (g0 + 32 < GS) {
            kreg = *(const int4*)(Kbase + (size_t)(g0 + 32) * 128);
            vreg = *(const int4*)(Vbase + (g0 + 32));
        }

        // scores: 2 row-subtiles x 2 key-subtiles
        f32x4 sc[2][2];
#pragma unroll
        for (int kt = 0; kt < 2; ++kt) {
            bf16x8 kf = zb;  // B[k=dim=quad*8+j][n=key=c]; dims>=16 zero
            if (quad < 2)
                kf = *(const bf16x8*)&Kt[(kt * 16 + c) * 136 + hh * 16 + quad * 8];
            sc[0][kt] = MFMA16(qf[0], kf, zf);
            sc[1][kt] = MFMA16(qf[1], kf, zf);
        }
        // V B-frag: B[k=key=quad*8+j][n=e=c]
        bf16x8 vf = *(const bf16x8*)&Vtt[(hh * 16 + c) * 36 + quad * 8];

        // max-free softmax: p = mask ? 0 : exp2(s); accumulate per-lane l
#pragma unroll
        for (int s = 0; s < 2; ++s) {
#pragma unroll
            for (int r = 0; r < 4; ++r) {
                int m0 = mb[(size_t)(s * 16 + r) * GS + g0];
                int m1 = mb[(size_t)(s * 16 + r) * GS + g0 + 16];
                float e0 = exp2f(sc[s][0][r]);
                float e1 = exp2f(sc[s][1][r]);
                e0 = m0 ? 0.f : e0;
                e1 = m1 ? 0.f : e1;
                ls[s][r] += e0 + e1;
                u32 u0 = __float_as_uint(e0) + 0x8000u;   // round-half-up bf16
                u32 u1 = __float_as_uint(e1) + 0x8000u;
                int row = s * 16 + quad * 4 + r;
                Ps[hh][row * 34 + c]      = (u16)(u0 >> 16);
                Ps[hh][row * 34 + 16 + c] = (u16)(u1 >> 16);
            }
        }

        // PV: A=P[m=row=c][k=key=quad*8+j] (same-wave LDS RAW, no barrier)
#pragma unroll
        for (int s = 0; s < 2; ++s) {
            bf16x8 pf = *(const bf16x8*)&Ps[hh][(s * 16 + c) * 34 + quad * 8];
            O[s] = MFMA16(pf, vf, O[s]);
        }
    }

    // reduce l over the 16 lanes of each quad (c dimension), then epilogue
#pragma unroll
    for (int s = 0; s < 2; ++s)
#pragma unroll
        for (int r = 0; r < 4; ++r) {
            float l = ls[s][r];
            l += __shfl_xor(l, 1);
            l += __shfl_xor(l, 2);
            l += __shfl_xor(l, 4);
            l += __shfl_xor(l, 8);
            float rl = (l > 0.f) ? 1.f / l : 0.f;
            heads[((size_t)b * NQ + q0 + s * 16 + quad * 4 + r) * 128 + hh * 16 + c] =
                O[s][r] * rl;
        }
}

extern "C" void kernel_launch(void* const* d_in, const int* in_sizes, int n_in,
                              void* d_out, int out_size, void* d_ws, size_t ws_size,
                              hipStream_t stream) {
    const float* q    = (const float*)d_in[0];
    const float* h    = (const float*)d_in[1];
    const int*   mask = (const int*)d_in[2];
    const float* Wq   = (const float*)d_in[3];
    const float* Wk   = (const float*)d_in[4];
    const float* Wv   = (const float*)d_in[5];
    const float* Wout = (const float*)d_in[6];
    float* out = (float*)d_out;

    const size_t NTOK = (size_t)NB * NQ;   // 32768
    u16* Qb  = (u16*)d_ws;                 // 8 MB each
    u16* Kb  = Qb + NTOK * 128;
    u16* Vtg = Kb + NTOK * 128;            // V transposed: [b][dim][token]
    float* Hw = (float*)(Vtg + NTOK * 128);// heads fp32, 16 MB

    proj_kernel<<<dim3(256, 3), 256, 0, stream>>>(q, h, Wq, Wk, Wv, Qb, Kb, Vtg);
    flash_mfma<<<dim3(NB, NQ / 32), 512, 0, stream>>>(Qb, Kb, Vtg, mask, Hw);
    outproj_kernel<<<dim3(256, 1), 256, 0, stream>>>(Hw, Wout, out);
}

// Round 4
// 360.299 us; speedup vs baseline: 8.0798x; 1.1638x over previous
//
#include <hip/hip_runtime.h>

typedef unsigned short u16;
typedef unsigned int   u32;
typedef short bf16x8 __attribute__((ext_vector_type(8)));
typedef float f32x4  __attribute__((ext_vector_type(4)));

#define NB  32
#define NQ  1024
#define GS  1024
#define NH  8
#define SCQ (0.25f * 1.4426950408889634f)   /* 1/sqrt(16) * log2(e) */

#define MFMA16(a, b, c) __builtin_amdgcn_mfma_f32_16x16x32_bf16(a, b, c, 0, 0, 0)

__device__ __forceinline__ u16 f2bf(float f) {  // RNE float->bf16 bits
    u32 u = __float_as_uint(f);
    return (u16)((u + 0x7fffu + ((u >> 16) & 1u)) >> 16);
}
__device__ __forceinline__ u32 pk2bf(float a, float b) {  // 2x round-half-up, packed
    u32 ua = (__float_as_uint(a) + 0x8000u) >> 16;
    u32 ub = (__float_as_uint(b) + 0x8000u) & 0xffff0000u;
    return ua | ub;
}

// ---------------------------------------------------------------------------
// Weight prep: Wp[m][col][k] bf16, 128x128 each.
//  m=0..2 (Wq/Wk/Wv [8][128][16]): col=h*16+e, k=d ; SCQ folded into m=0.
//  m=3 (Wout [8][16][128]):        col=d, k=h*16+e.
// ---------------------------------------------------------------------------
__global__ __launch_bounds__(256) void wprep(const float* __restrict__ Wq,
                                             const float* __restrict__ Wk,
                                             const float* __restrict__ Wv,
                                             const float* __restrict__ Wout,
                                             u16* __restrict__ Wp) {
    int m = blockIdx.x;
    const float* src = (m == 0) ? Wq : (m == 1) ? Wk : (m == 2) ? Wv : Wout;
    float scale = (m == 0) ? SCQ : 1.0f;
    for (int i = threadIdx.x; i < 16384; i += 256) {
        int cc = i >> 7, k = i & 127;
        float v;
        if (m < 3) v = src[(cc >> 4) * 2048 + k * 16 + (cc & 15)];
        else       v = src[(k >> 4) * 2048 + (k & 15) * 128 + cc];
        Wp[m * 16384 + cc * 128 + k] = f2bf(v * scale);
    }
}

// ---------------------------------------------------------------------------
// MFMA GEMM: C[128 x 128] = A[128 x 128] * Wp^T, K=128 staged once.
// 256 thr = 4 waves; wave wv owns rows wv*32..+31, all 128 cols.
// AIN 0: A fp32 (convert to bf16 in staging); AIN 1: A bf16 (copy).
// MODE 0: bf16 out row-major; MODE 1: fp32 out; MODE 2: bf16 out transposed
//         per batch (Vt_g[b][col][token]).
// ---------------------------------------------------------------------------
template <int MODE, int AIN>
__device__ __forceinline__ void mgemm(const void* __restrict__ Ain,
                                      const u16* __restrict__ Wp,
                                      float* __restrict__ outf,
                                      u16* __restrict__ outb,
                                      u16* As, u16* Ws, int row0) {
    const int t    = threadIdx.x;
    const int wv   = t >> 6;
    const int lane = t & 63;
    const int quad = lane >> 4;
    const int c    = lane & 15;

    // stage A tile: rows row0..+127, k 0..127
#pragma unroll
    for (int g0 = 0; g0 < 2048; g0 += 256) {
        int g = g0 + t;
        int row = g >> 4, k0 = (g & 15) * 8;
        if (AIN == 0) {
            const float4* ap =
                (const float4*)&((const float*)Ain)[(size_t)(row0 + row) * 128 + k0];
            float4 a0 = ap[0], a1 = ap[1];
            int4 pk;
            pk.x = (int)pk2bf(a0.x, a0.y);
            pk.y = (int)pk2bf(a0.z, a0.w);
            pk.z = (int)pk2bf(a1.x, a1.y);
            pk.w = (int)pk2bf(a1.z, a1.w);
            *(int4*)&As[row * 136 + k0] = pk;
        } else {
            *(int4*)&As[row * 136 + k0] =
                *(const int4*)&((const u16*)Ain)[(size_t)(row0 + row) * 128 + k0];
        }
    }
    // stage W tile (already [col][k] bf16)
#pragma unroll
    for (int g0 = 0; g0 < 2048; g0 += 256) {
        int g = g0 + t;
        int cc = g >> 4, k0 = (g & 15) * 8;
        *(int4*)&Ws[cc * 136 + k0] = *(const int4*)&Wp[cc * 128 + k0];
    }
    __syncthreads();

    const f32x4 zf = {0.f, 0.f, 0.f, 0.f};
    f32x4 acc[2][8];
#pragma unroll
    for (int s = 0; s < 2; ++s)
#pragma unroll
        for (int j = 0; j < 8; ++j) acc[s][j] = zf;

#pragma unroll
    for (int kt = 0; kt < 4; ++kt) {
        bf16x8 af0 = *(const bf16x8*)&As[(wv * 32 + c) * 136 + kt * 32 + quad * 8];
        bf16x8 af1 = *(const bf16x8*)&As[(wv * 32 + 16 + c) * 136 + kt * 32 + quad * 8];
#pragma unroll
        for (int j = 0; j < 8; ++j) {
            bf16x8 bfr = *(const bf16x8*)&Ws[(j * 16 + c) * 136 + kt * 32 + quad * 8];
            acc[0][j] = MFMA16(af0, bfr, acc[0][j]);
            acc[1][j] = MFMA16(af1, bfr, acc[1][j]);
        }
    }

    // epilogue: C row = row0 + wv*32 + s*16 + quad*4 + r, col = j*16 + c
#pragma unroll
    for (int s = 0; s < 2; ++s)
#pragma unroll
        for (int j = 0; j < 8; ++j)
#pragma unroll
            for (int r = 0; r < 4; ++r) {
                int row = row0 + wv * 32 + s * 16 + quad * 4 + r;
                int col = j * 16 + c;
                float v = acc[s][j][r];
                if (MODE == 0) {
                    outb[(size_t)row * 128 + col] = f2bf(v);
                } else if (MODE == 2) {
                    int bI = row >> 10, tb = row & 1023;
                    outb[(size_t)bI * (128 * 1024) + (size_t)col * 1024 + tb] = f2bf(v);
                } else {
                    outf[(size_t)row * 128 + col] = v;
                }
            }
}

__global__ __launch_bounds__(256, 2) void proj_mfma(const float* __restrict__ q,
                                                    const float* __restrict__ h,
                                                    const u16* __restrict__ Wp,
                                                    u16* __restrict__ Qb,
                                                    u16* __restrict__ Kb,
                                                    u16* __restrict__ Vtg) {
    __shared__ u16 As[128 * 136];
    __shared__ u16 Ws[128 * 136];
    int row0 = blockIdx.x * 128;
    if (blockIdx.y == 0)      mgemm<0, 0>(q, Wp,         nullptr, Qb, As, Ws, row0);
    else if (blockIdx.y == 1) mgemm<0, 0>(h, Wp + 16384, nullptr, Kb, As, Ws, row0);
    else                      mgemm<2, 0>(h, Wp + 32768, nullptr, Vtg, As, Ws, row0);
}

__global__ __launch_bounds__(256, 2) void outproj_mfma(const u16* __restrict__ headsb,
                                                       const u16* __restrict__ Wp,
                                                       float* __restrict__ out) {
    __shared__ u16 As[128 * 136];
    __shared__ u16 Ws[128 * 136];
    mgemm<1, 1>(headsb, Wp + 49152, out, nullptr, As, Ws, blockIdx.x * 128);
}

// ---------------------------------------------------------------------------
// MFMA flash attention (unchanged from R3 except bf16 heads output).
// ---------------------------------------------------------------------------
__global__ __launch_bounds__(512, 4) void flash_mfma(const u16* __restrict__ Qb,
                                                     const u16* __restrict__ Kb,
                                                     const u16* __restrict__ Vtg,
                                                     const int* __restrict__ mask,
                                                     u16* __restrict__ headsb) {
    __shared__ u16 Kt[32 * 136];        // [key][dim], stride 136
    __shared__ u16 Vtt[128 * 36];       // [dim][key], stride 36
    __shared__ u16 Ps[NH][32 * 34];     // per-wave P [row][key], stride 34

    const int b    = blockIdx.x;
    const int q0   = blockIdx.y * 32;
    const int t    = threadIdx.x;
    const int hh   = t >> 6;
    const int lane = t & 63;
    const int quad = lane >> 4;
    const int c    = lane & 15;

    const f32x4  zf = {0.f, 0.f, 0.f, 0.f};
    const bf16x8 zb = {0, 0, 0, 0, 0, 0, 0, 0};

    bf16x8 qf[2];
#pragma unroll
    for (int s = 0; s < 2; ++s) {
        qf[s] = zb;
        if (quad < 2)
            qf[s] = *(const bf16x8*)&Qb[((size_t)b * NQ + q0 + s * 16 + c) * 128 +
                                        hh * 16 + quad * 8];
    }

    f32x4 O[2] = {zf, zf};
    float ls[2][4] = {{0.f, 0.f, 0.f, 0.f}, {0.f, 0.f, 0.f, 0.f}};

    const int skey = t >> 4;
    const int sd0  = (t & 15) * 8;
    const int vdim = t >> 2;
    const int vk0  = (t & 3) * 8;

    const u16* Kbase = &Kb[((size_t)b * GS + skey) * 128 + sd0];
    const u16* Vbase = &Vtg[(size_t)b * (128 * 1024) + (size_t)vdim * 1024 + vk0];
    const int* mb    = mask + ((size_t)b * NQ + q0 + quad * 4) * GS + c;

    int4 kreg = *(const int4*)Kbase;
    int4 vreg = *(const int4*)Vbase;

    for (int g0 = 0; g0 < GS; g0 += 32) {
        __syncthreads();
        *(int4*)&Kt[skey * 136 + sd0] = kreg;
        *(int4*)&Vtt[vdim * 36 + vk0] = vreg;
        __syncthreads();

        if (g0 + 32 < GS) {
            kreg = *(const int4*)(Kbase + (size_t)(g0 + 32) * 128);
            vreg = *(const int4*)(Vbase + (g0 + 32));
        }

        f32x4 sc[2][2];
#pragma unroll
        for (int kt = 0; kt < 2; ++kt) {
            bf16x8 kf = zb;
            if (quad < 2)
                kf = *(const bf16x8*)&Kt[(kt * 16 + c) * 136 + hh * 16 + quad * 8];
            sc[0][kt] = MFMA16(qf[0], kf, zf);
            sc[1][kt] = MFMA16(qf[1], kf, zf);
        }
        bf16x8 vf = *(const bf16x8*)&Vtt[(hh * 16 + c) * 36 + quad * 8];

#pragma unroll
        for (int s = 0; s < 2; ++s) {
#pragma unroll
            for (int r = 0; r < 4; ++r) {
                int m0 = mb[(size_t)(s * 16 + r) * GS + g0];
                int m1 = mb[(size_t)(s * 16 + r) * GS + g0 + 16];
                float e0 = exp2f(sc[s][0][r]);
                float e1 = exp2f(sc[s][1][r]);
                e0 = m0 ? 0.f : e0;
                e1 = m1 ? 0.f : e1;
                ls[s][r] += e0 + e1;
                u32 u0 = __float_as_uint(e0) + 0x8000u;
                u32 u1 = __float_as_uint(e1) + 0x8000u;
                int row = s * 16 + quad * 4 + r;
                Ps[hh][row * 34 + c]      = (u16)(u0 >> 16);
                Ps[hh][row * 34 + 16 + c] = (u16)(u1 >> 16);
            }
        }

#pragma unroll
        for (int s = 0; s < 2; ++s) {
            bf16x8 pf = *(const bf16x8*)&Ps[hh][(s * 16 + c) * 34 + quad * 8];
            O[s] = MFMA16(pf, vf, O[s]);
        }
    }

#pragma unroll
    for (int s = 0; s < 2; ++s)
#pragma unroll
        for (int r = 0; r < 4; ++r) {
            float l = ls[s][r];
            l += __shfl_xor(l, 1);
            l += __shfl_xor(l, 2);
            l += __shfl_xor(l, 4);
            l += __shfl_xor(l, 8);
            float rl = (l > 0.f) ? 1.f / l : 0.f;
            headsb[((size_t)b * NQ + q0 + s * 16 + quad * 4 + r) * 128 + hh * 16 + c] =
                f2bf(O[s][r] * rl);
        }
}

extern "C" void kernel_launch(void* const* d_in, const int* in_sizes, int n_in,
                              void* d_out, int out_size, void* d_ws, size_t ws_size,
                              hipStream_t stream) {
    const float* q    = (const float*)d_in[0];
    const float* h    = (const float*)d_in[1];
    const int*   mask = (const int*)d_in[2];
    const float* Wq   = (const float*)d_in[3];
    const float* Wk   = (const float*)d_in[4];
    const float* Wv   = (const float*)d_in[5];
    const float* Wout = (const float*)d_in[6];
    float* out = (float*)d_out;

    const size_t NTOK = (size_t)NB * NQ;     // 32768
    u16* Qb  = (u16*)d_ws;                   // 8 MB each
    u16* Kb  = Qb + NTOK * 128;
    u16* Vtg = Kb + NTOK * 128;              // V transposed: [b][dim][token]
    u16* Hb  = Vtg + NTOK * 128;             // heads bf16, 8 MB
    u16* Wp  = Hb + NTOK * 128;              // prepped weights, 128 KB

    wprep<<<dim3(4), 256, 0, stream>>>(Wq, Wk, Wv, Wout, Wp);
    proj_mfma<<<dim3(256, 3), 256, 0, stream>>>(q, h, Wp, Qb, Kb, Vtg);
    flash_mfma<<<dim3(NB, NQ / 32), 512, 0, stream>>>(Qb, Kb, Vtg, mask, Hb);
    outproj_mfma<<<dim3(256, 1), 256, 0, stream>>>(Hb, Wp, out);
}

// Round 5
// 322.841 us; speedup vs baseline: 9.0173x; 1.1160x over previous
//
#include <hip/hip_runtime.h>

typedef unsigned short u16;
typedef unsigned int   u32;
typedef short bf16x8 __attribute__((ext_vector_type(8)));
typedef float f32x4  __attribute__((ext_vector_type(4)));

#define NB  32
#define NQ  1024
#define GS  1024
#define NH  8
#define SCQ (0.25f * 1.4426950408889634f)   /* 1/sqrt(16) * log2(e) */

#define MFMA16(a, b, c) __builtin_amdgcn_mfma_f32_16x16x32_bf16(a, b, c, 0, 0, 0)

__device__ __forceinline__ u16 f2bf(float f) {  // RNE float->bf16 bits
    u32 u = __float_as_uint(f);
    return (u16)((u + 0x7fffu + ((u >> 16) & 1u)) >> 16);
}
__device__ __forceinline__ u32 pk2bf(float a, float b) {  // 2x round-half-up, packed
    u32 ua = (__float_as_uint(a) + 0x8000u) >> 16;
    u32 ub = (__float_as_uint(b) + 0x8000u) & 0xffff0000u;
    return ua | ub;
}

// ---------------------------------------------------------------------------
// MFMA GEMM: C[128 x 128] = A[128 x 128] * W^T, K=128 staged once.
// 256 thr = 4 waves; wave wv owns rows wv*32..+31, all 128 cols.
// AIN 0: A fp32 (convert in staging); AIN 1: A bf16 (copy).
// WMODE 0: W=[8][128][16] fp32 (Wq/Wk/Wv), col=16h+e, k=d, scale folded.
// WMODE 1: W=[8][16][128] fp32 (Wout), col=d, k=16h+e.
// MODE 0: bf16 out row-major; MODE 1: fp32 out; MODE 2: bf16 out transposed
//         per batch (Vt_g[b][col][token]).
// ---------------------------------------------------------------------------
template <int MODE, int AIN, int WMODE>
__device__ __forceinline__ void mgemm(const void* __restrict__ Ain,
                                      const float* __restrict__ Wsrc,
                                      float wscale,
                                      float* __restrict__ outf,
                                      u16* __restrict__ outb,
                                      u16* As, u16* Ws, int row0) {
    const int t    = threadIdx.x;
    const int wv   = t >> 6;
    const int lane = t & 63;
    const int quad = lane >> 4;
    const int c    = lane & 15;

    // stage A tile: rows row0..+127, k 0..127
#pragma unroll
    for (int g0 = 0; g0 < 2048; g0 += 256) {
        int g = g0 + t;
        int row = g >> 4, k0 = (g & 15) * 8;
        if (AIN == 0) {
            const float4* ap =
                (const float4*)&((const float*)Ain)[(size_t)(row0 + row) * 128 + k0];
            float4 a0 = ap[0], a1 = ap[1];
            int4 pk;
            pk.x = (int)pk2bf(a0.x, a0.y);
            pk.y = (int)pk2bf(a0.z, a0.w);
            pk.z = (int)pk2bf(a1.x, a1.y);
            pk.w = (int)pk2bf(a1.z, a1.w);
            *(int4*)&As[row * 136 + k0] = pk;
        } else {
            *(int4*)&As[row * 136 + k0] =
                *(const int4*)&((const u16*)Ain)[(size_t)(row0 + row) * 128 + k0];
        }
    }
    // stage W tile directly from fp32 source (coalesced read, b16 LDS scatter)
#pragma unroll
    for (int i0 = 0; i0 < 16384; i0 += 256) {
        int i = i0 + t;
        float v = Wsrc[i];
        if (WMODE == 0) {
            int hh = i >> 11, d = (i >> 4) & 127, e = i & 15;
            Ws[(hh * 16 + e) * 136 + d] = f2bf(v * wscale);
        } else {
            int he = i >> 7, d = i & 127;
            Ws[d * 136 + he] = f2bf(v);
        }
    }
    __syncthreads();

    const f32x4 zf = {0.f, 0.f, 0.f, 0.f};
    f32x4 acc[2][8];
#pragma unroll
    for (int s = 0; s < 2; ++s)
#pragma unroll
        for (int j = 0; j < 8; ++j) acc[s][j] = zf;

#pragma unroll
    for (int kt = 0; kt < 4; ++kt) {
        bf16x8 af0 = *(const bf16x8*)&As[(wv * 32 + c) * 136 + kt * 32 + quad * 8];
        bf16x8 af1 = *(const bf16x8*)&As[(wv * 32 + 16 + c) * 136 + kt * 32 + quad * 8];
#pragma unroll
        for (int j = 0; j < 8; ++j) {
            bf16x8 bfr = *(const bf16x8*)&Ws[(j * 16 + c) * 136 + kt * 32 + quad * 8];
            acc[0][j] = MFMA16(af0, bfr, acc[0][j]);
            acc[1][j] = MFMA16(af1, bfr, acc[1][j]);
        }
    }

    // epilogue: C row = row0 + wv*32 + s*16 + quad*4 + r, col = j*16 + c
#pragma unroll
    for (int s = 0; s < 2; ++s)
#pragma unroll
        for (int j = 0; j < 8; ++j)
#pragma unroll
            for (int r = 0; r < 4; ++r) {
                int row = row0 + wv * 32 + s * 16 + quad * 4 + r;
                int col = j * 16 + c;
                float v = acc[s][j][r];
                if (MODE == 0) {
                    outb[(size_t)row * 128 + col] = f2bf(v);
                } else if (MODE == 2) {
                    int bI = row >> 10, tb = row & 1023;
                    outb[(size_t)bI * (128 * 1024) + (size_t)col * 1024 + tb] = f2bf(v);
                } else {
                    outf[(size_t)row * 128 + col] = v;
                }
            }
}

__global__ __launch_bounds__(256, 2) void proj_mfma(const float* __restrict__ q,
                                                    const float* __restrict__ h,
                                                    const float* __restrict__ Wq,
                                                    const float* __restrict__ Wk,
                                                    const float* __restrict__ Wv,
                                                    u16* __restrict__ Qb,
                                                    u16* __restrict__ Kb,
                                                    u16* __restrict__ Vtg) {
    __shared__ u16 As[128 * 136];
    __shared__ u16 Ws[128 * 136];
    int row0 = blockIdx.x * 128;
    if (blockIdx.y == 0)      mgemm<0, 0, 0>(q, Wq, SCQ,  nullptr, Qb,  As, Ws, row0);
    else if (blockIdx.y == 1) mgemm<0, 0, 0>(h, Wk, 1.0f, nullptr, Kb,  As, Ws, row0);
    else                      mgemm<2, 0, 0>(h, Wv, 1.0f, nullptr, Vtg, As, Ws, row0);
}

__global__ __launch_bounds__(256, 2) void outproj_mfma(const u16* __restrict__ headsb,
                                                       const float* __restrict__ Wout,
                                                       float* __restrict__ out) {
    __shared__ u16 As[128 * 136];
    __shared__ u16 Ws[128 * 136];
    mgemm<1, 1, 1>(headsb, Wout, 1.0f, out, nullptr, As, Ws, blockIdx.x * 128);
}

// ---------------------------------------------------------------------------
// MFMA flash attention, max-free softmax (scores bounded; exp2 domain).
// Block = (batch, 32 q-rows), 512 thr = 8 waves = 8 heads.
// Mask tile (32x32 int) staged in LDS via coalesced int2 (prefetched),
// read back as broadcast-friendly ds_read_b32 (stride 34, <=2-way banks).
// Ps stride 36 -> pf b128 reads <=2-way (was 4-way at 34).
// ---------------------------------------------------------------------------
__global__ __launch_bounds__(512, 4) void flash_mfma(const u16* __restrict__ Qb,
                                                     const u16* __restrict__ Kb,
                                                     const u16* __restrict__ Vtg,
                                                     const int* __restrict__ mask,
                                                     u16* __restrict__ headsb) {
    __shared__ u16 Kt[32 * 136];        // [key][dim], stride 136
    __shared__ u16 Vtt[128 * 36];       // [dim][key], stride 36
    __shared__ u16 Ps[NH][32 * 36];     // per-wave P [row][key], stride 36
    __shared__ int Mt[32 * 34];         // mask tile [row][key], stride 34

    const int b    = blockIdx.x;
    const int q0   = blockIdx.y * 32;
    const int t    = threadIdx.x;
    const int hh   = t >> 6;
    const int lane = t & 63;
    const int quad = lane >> 4;
    const int c    = lane & 15;

    const f32x4  zf = {0.f, 0.f, 0.f, 0.f};
    const bf16x8 zb = {0, 0, 0, 0, 0, 0, 0, 0};

    bf16x8 qf[2];
#pragma unroll
    for (int s = 0; s < 2; ++s) {
        qf[s] = zb;
        if (quad < 2)
            qf[s] = *(const bf16x8*)&Qb[((size_t)b * NQ + q0 + s * 16 + c) * 128 +
                                        hh * 16 + quad * 8];
    }

    f32x4 O[2] = {zf, zf};
    float ls[2][4] = {{0.f, 0.f, 0.f, 0.f}, {0.f, 0.f, 0.f, 0.f}};

    // staging indices
    const int skey = t >> 4;            // K: key 0..31, dim octet (t&15)*8
    const int sd0  = (t & 15) * 8;
    const int vdim = t >> 2;            // V: dim 0..127, key octet (t&3)*8
    const int vk0  = (t & 3) * 8;
    const int mrow = t >> 4;            // M: row 0..31, key pair (t&15)*2
    const int mk0  = (t & 15) * 2;

    const u16* Kbase = &Kb[((size_t)b * GS + skey) * 128 + sd0];
    const u16* Vbase = &Vtg[(size_t)b * (128 * 1024) + (size_t)vdim * 1024 + vk0];
    const int* Mbase = &mask[((size_t)b * NQ + q0 + mrow) * GS + mk0];

    int4 kreg = *(const int4*)Kbase;
    int4 vreg = *(const int4*)Vbase;
    int2 mreg = *(const int2*)Mbase;

    for (int g0 = 0; g0 < GS; g0 += 32) {
        __syncthreads();
        *(int4*)&Kt[skey * 136 + sd0] = kreg;
        *(int4*)&Vtt[vdim * 36 + vk0] = vreg;
        *(int2*)&Mt[mrow * 34 + mk0]  = mreg;
        __syncthreads();

        if (g0 + 32 < GS) {
            kreg = *(const int4*)(Kbase + (size_t)(g0 + 32) * 128);
            vreg = *(const int4*)(Vbase + (g0 + 32));
            mreg = *(const int2*)(Mbase + (g0 + 32));
        }

        f32x4 sc[2][2];
#pragma unroll
        for (int kt = 0; kt < 2; ++kt) {
            bf16x8 kf = zb;
            if (quad < 2)
                kf = *(const bf16x8*)&Kt[(kt * 16 + c) * 136 + hh * 16 + quad * 8];
            sc[0][kt] = MFMA16(qf[0], kf, zf);
            sc[1][kt] = MFMA16(qf[1], kf, zf);
        }
        bf16x8 vf = *(const bf16x8*)&Vtt[(hh * 16 + c) * 36 + quad * 8];

#pragma unroll
        for (int s = 0; s < 2; ++s) {
#pragma unroll
            for (int r = 0; r < 4; ++r) {
                int mtrow = (s * 16 + quad * 4 + r) * 34;
                int m0 = Mt[mtrow + c];
                int m1 = Mt[mtrow + 16 + c];
                float e0 = exp2f(sc[s][0][r]);
                float e1 = exp2f(sc[s][1][r]);
                e0 = m0 ? 0.f : e0;
                e1 = m1 ? 0.f : e1;
                ls[s][r] += e0 + e1;
                u32 u0 = __float_as_uint(e0) + 0x8000u;
                u32 u1 = __float_as_uint(e1) + 0x8000u;
                int row = s * 16 + quad * 4 + r;
                Ps[hh][row * 36 + c]      = (u16)(u0 >> 16);
                Ps[hh][row * 36 + 16 + c] = (u16)(u1 >> 16);
            }
        }

#pragma unroll
        for (int s = 0; s < 2; ++s) {
            bf16x8 pf = *(const bf16x8*)&Ps[hh][(s * 16 + c) * 36 + quad * 8];
            O[s] = MFMA16(pf, vf, O[s]);
        }
    }

#pragma unroll
    for (int s = 0; s < 2; ++s)
#pragma unroll
        for (int r = 0; r < 4; ++r) {
            float l = ls[s][r];
            l += __shfl_xor(l, 1);
            l += __shfl_xor(l, 2);
            l += __shfl_xor(l, 4);
            l += __shfl_xor(l, 8);
            float rl = (l > 0.f) ? 1.f / l : 0.f;
            headsb[((size_t)b * NQ + q0 + s * 16 + quad * 4 + r) * 128 + hh * 16 + c] =
                f2bf(O[s][r] * rl);
        }
}

extern "C" void kernel_launch(void* const* d_in, const int* in_sizes, int n_in,
                              void* d_out, int out_size, void* d_ws, size_t ws_size,
                              hipStream_t stream) {
    const float* q    = (const float*)d_in[0];
    const float* h    = (const float*)d_in[1];
    const int*   mask = (const int*)d_in[2];
    const float* Wq   = (const float*)d_in[3];
    const float* Wk   = (const float*)d_in[4];
    const float* Wv   = (const float*)d_in[5];
    const float* Wout = (const float*)d_in[6];
    float* out = (float*)d_out;

    const size_t NTOK = (size_t)NB * NQ;     // 32768
    u16* Qb  = (u16*)d_ws;                   // 8 MB each
    u16* Kb  = Qb + NTOK * 128;
    u16* Vtg = Kb + NTOK * 128;              // V transposed: [b][dim][token]
    u16* Hb  = Vtg + NTOK * 128;             // heads bf16, 8 MB

    proj_mfma<<<dim3(256, 3), 256, 0, stream>>>(q, h, Wq, Wk, Wv, Qb, Kb, Vtg);
    flash_mfma<<<dim3(NB, NQ / 32), 512, 0, stream>>>(Qb, Kb, Vtg, mask, Hb);
    outproj_mfma<<<dim3(256, 1), 256, 0, stream>>>(Hb, Wout, out);
}

// Round 6
// 322.787 us; speedup vs baseline: 9.0188x; 1.0002x over previous
//
#include <hip/hip_runtime.h>

typedef unsigned short u16;
typedef unsigned int   u32;
typedef short bf16x8 __attribute__((ext_vector_type(8)));
typedef float f32x4  __attribute__((ext_vector_type(4)));

#define NB  32
#define NQ  1024
#define GS  1024
#define NH  8
#define SCQ (0.25f * 1.4426950408889634f)   /* 1/sqrt(16) * log2(e) */
#define MBIG (-1.0e30f)

#define MFMA16(a, b, c) __builtin_amdgcn_mfma_f32_16x16x32_bf16(a, b, c, 0, 0, 0)

__device__ __forceinline__ u16 f2bf(float f) {  // RNE float->bf16 bits
    u32 u = __float_as_uint(f);
    return (u16)((u + 0x7fffu + ((u >> 16) & 1u)) >> 16);
}
__device__ __forceinline__ u32 pk2bf(float a, float b) {  // 2x round-half-up, packed
    u32 ua = (__float_as_uint(a) + 0x8000u) >> 16;
    u32 ub = (__float_as_uint(b) + 0x8000u) & 0xffff0000u;
    return ua | ub;
}
__device__ __forceinline__ u32 packbf2(float a, float b) { // (a=lo, b=hi)
#if __has_builtin(__builtin_amdgcn_cvt_pk_bf16_f32)
    auto pk = __builtin_amdgcn_cvt_pk_bf16_f32(a, b);
    u32 w;
    __builtin_memcpy(&w, &pk, 4);
    return w;
#else
    return pk2bf(a, b);
#endif
}

// ---------------------------------------------------------------------------
// MFMA GEMM: C[128x128] = A[128x128] * W^T, K=128 staged once.
// 256 thr = 4 waves; A fp32 -> bf16 in staging; W=[8][128][16] fp32,
// col=16h+e, k=d, scale folded. MODE 0: bf16 out row-major;
// MODE 2: bf16 out transposed per batch (Vt_g[b][col][token]).
// ---------------------------------------------------------------------------
template <int MODE>
__device__ __forceinline__ void mgemm(const float* __restrict__ Ain,
                                      const float* __restrict__ Wsrc,
                                      float wscale,
                                      u16* __restrict__ outb,
                                      u16* As, u16* Ws, int row0) {
    const int t    = threadIdx.x;
    const int wv   = t >> 6;
    const int lane = t & 63;
    const int quad = lane >> 4;
    const int c    = lane & 15;

#pragma unroll
    for (int g0 = 0; g0 < 2048; g0 += 256) {
        int g = g0 + t;
        int row = g >> 4, k0 = (g & 15) * 8;
        const float4* ap = (const float4*)&Ain[(size_t)(row0 + row) * 128 + k0];
        float4 a0 = ap[0], a1 = ap[1];
        int4 pk;
        pk.x = (int)pk2bf(a0.x, a0.y);
        pk.y = (int)pk2bf(a0.z, a0.w);
        pk.z = (int)pk2bf(a1.x, a1.y);
        pk.w = (int)pk2bf(a1.z, a1.w);
        *(int4*)&As[row * 136 + k0] = pk;
    }
#pragma unroll
    for (int i0 = 0; i0 < 16384; i0 += 256) {
        int i = i0 + t;
        float v = Wsrc[i];
        int hh = i >> 11, d = (i >> 4) & 127, e = i & 15;
        Ws[(hh * 16 + e) * 136 + d] = f2bf(v * wscale);
    }
    __syncthreads();

    const f32x4 zf = {0.f, 0.f, 0.f, 0.f};
    f32x4 acc[2][8];
#pragma unroll
    for (int s = 0; s < 2; ++s)
#pragma unroll
        for (int j = 0; j < 8; ++j) acc[s][j] = zf;

#pragma unroll
    for (int kt = 0; kt < 4; ++kt) {
        bf16x8 af0 = *(const bf16x8*)&As[(wv * 32 + c) * 136 + kt * 32 + quad * 8];
        bf16x8 af1 = *(const bf16x8*)&As[(wv * 32 + 16 + c) * 136 + kt * 32 + quad * 8];
#pragma unroll
        for (int j = 0; j < 8; ++j) {
            bf16x8 bfr = *(const bf16x8*)&Ws[(j * 16 + c) * 136 + kt * 32 + quad * 8];
            acc[0][j] = MFMA16(af0, bfr, acc[0][j]);
            acc[1][j] = MFMA16(af1, bfr, acc[1][j]);
        }
    }

#pragma unroll
    for (int s = 0; s < 2; ++s)
#pragma unroll
        for (int j = 0; j < 8; ++j)
#pragma unroll
            for (int r = 0; r < 4; ++r) {
                int row = row0 + wv * 32 + s * 16 + quad * 4 + r;
                int col = j * 16 + c;
                float v = acc[s][j][r];
                if (MODE == 0) {
                    outb[(size_t)row * 128 + col] = f2bf(v);
                } else {
                    int bI = row >> 10, tb = row & 1023;
                    outb[(size_t)bI * (128 * 1024) + (size_t)col * 1024 + tb] = f2bf(v);
                }
            }
}

// Also preps Wob[d][16h+e] = Wout[h][e][d] bf16 (block (0,0) only).
__global__ __launch_bounds__(256, 2) void proj_mfma(const float* __restrict__ q,
                                                    const float* __restrict__ h,
                                                    const float* __restrict__ Wq,
                                                    const float* __restrict__ Wk,
                                                    const float* __restrict__ Wv,
                                                    const float* __restrict__ Wout,
                                                    u16* __restrict__ Qb,
                                                    u16* __restrict__ Kb,
                                                    u16* __restrict__ Vtg,
                                                    u16* __restrict__ Wob) {
    __shared__ u16 As[128 * 136];
    __shared__ u16 Ws[128 * 136];
    int row0 = blockIdx.x * 128;
    if (blockIdx.y == 0 && blockIdx.x == 0) {
        for (int i = threadIdx.x; i < 16384; i += 256) {
            int d = i >> 7, k = i & 127, hh = k >> 4, e = k & 15;
            Wob[i] = f2bf(Wout[hh * 2048 + e * 128 + d]);
        }
    }
    if (blockIdx.y == 0)      mgemm<0>(q, Wq, SCQ,  Qb,  As, Ws, row0);
    else if (blockIdx.y == 1) mgemm<0>(h, Wk, 1.0f, Kb,  As, Ws, row0);
    else                      mgemm<2>(h, Wv, 1.0f, Vtg, As, Ws, row0);
}

// ---------------------------------------------------------------------------
// MFMA flash attention + fused out-projection.
// Block = (batch, 32 q-rows), 512 thr = 8 waves = 8 heads.
// Mask folded into score-MFMA C operand as {0,-1e30} floats (Mf, col-major
// [key][row] stride 36 -> b128 C-frag reads). exp2(-1e30)=+0 handles masking.
// P packed 2 keys/u32 in interleaved key order; V staged in the SAME key
// order so the PV contraction is invariant. Epilogue: heads -> LDS (reuses
// Kt) -> 8 MFMAs/wave vs global bf16 Wob -> fp32 out.
// LDS: 8704+9216+18432+4608 = 40960 B exactly -> 4 blocks/CU.
// ---------------------------------------------------------------------------
__global__ __launch_bounds__(512, 4) void flash_mfma(const u16* __restrict__ Qb,
                                                     const u16* __restrict__ Kb,
                                                     const u16* __restrict__ Vtg,
                                                     const int* __restrict__ mask,
                                                     const u16* __restrict__ Wob,
                                                     float* __restrict__ out) {
    __shared__ u16 Kt[32 * 136];        // [key][dim]; reused as Hs after loop
    __shared__ u16 Vtt[128 * 36];       // [dim][key-slot], slot = 2(g&15)+(g>>4)
    __shared__ u16 Ps[NH][32 * 36];     // per-wave P [row][key-slot]
    __shared__ float Mf[32 * 36];       // mask add [key][row], stride 36

    const int b    = blockIdx.x;
    const int q0   = blockIdx.y * 32;
    const int t    = threadIdx.x;
    const int hh   = t >> 6;
    const int lane = t & 63;
    const int quad = lane >> 4;
    const int c    = lane & 15;

    const f32x4  zf = {0.f, 0.f, 0.f, 0.f};
    const bf16x8 zb = {0, 0, 0, 0, 0, 0, 0, 0};

    bf16x8 qf[2];
#pragma unroll
    for (int s = 0; s < 2; ++s) {
        qf[s] = zb;
        if (quad < 2)
            qf[s] = *(const bf16x8*)&Qb[((size_t)b * NQ + q0 + s * 16 + c) * 128 +
                                        hh * 16 + quad * 8];
    }

    f32x4 O[2] = {zf, zf};
    float ls[2][4] = {{0.f, 0.f, 0.f, 0.f}, {0.f, 0.f, 0.f, 0.f}};

    // staging indices
    const int skey = t >> 4;            // K: key 0..31, dim octet (t&15)*8
    const int sd0  = (t & 15) * 8;
    const int vdim = t >> 2;            // V: dim 0..127, token quad vq
    const int vq   = t & 3;
    const int mrow = t >> 4;            // M: row 0..31, key pair (t&15)*2
    const int mk0  = (t & 15) * 2;

    const u16* Kbase = &Kb[((size_t)b * GS + skey) * 128 + sd0];
    const u16* Vbase = &Vtg[(size_t)b * (128 * 1024) + (size_t)vdim * 1024];
    const int* Mbase = &mask[((size_t)b * NQ + q0 + mrow) * GS + mk0];

    int4 kreg = *(const int4*)Kbase;
    int2 va   = *(const int2*)(Vbase + vq * 4);        // tokens vq*4..+3
    int2 vb   = *(const int2*)(Vbase + 16 + vq * 4);   // tokens 16+vq*4..+3
    int2 mreg = *(const int2*)Mbase;

    for (int g0 = 0; g0 < GS; g0 += 32) {
        __syncthreads();
        *(int4*)&Kt[skey * 136 + sd0] = kreg;
        {   // interleave: slots 8*vq+i <-> keys {4vq,16+4vq,4vq+1,16+4vq+1,...}
            int4 w;
            w.x = (int)(((u32)va.x & 0xffffu) | ((u32)vb.x << 16));
            w.y = (int)(((u32)va.x >> 16) | ((u32)vb.x & 0xffff0000u));
            w.z = (int)(((u32)va.y & 0xffffu) | ((u32)vb.y << 16));
            w.w = (int)(((u32)va.y >> 16) | ((u32)vb.y & 0xffff0000u));
            *(int4*)&Vtt[vdim * 36 + vq * 8] = w;
        }
        Mf[mk0 * 36 + mrow]       = mreg.x ? MBIG : 0.f;
        Mf[(mk0 + 1) * 36 + mrow] = mreg.y ? MBIG : 0.f;
        __syncthreads();

        if (g0 + 32 < GS) {
            kreg = *(const int4*)(Kbase + (size_t)(g0 + 32) * 128);
            va   = *(const int2*)(Vbase + g0 + 32 + vq * 4);
            vb   = *(const int2*)(Vbase + g0 + 48 + vq * 4);
            mreg = *(const int2*)(Mbase + (g0 + 32));
        }

        // scores with mask pre-loaded into C
        f32x4 sc[2][2];
#pragma unroll
        for (int kt = 0; kt < 2; ++kt) {
            bf16x8 kf = zb;
            if (quad < 2)
                kf = *(const bf16x8*)&Kt[(kt * 16 + c) * 136 + hh * 16 + quad * 8];
#pragma unroll
            for (int s = 0; s < 2; ++s) {
                f32x4 c0 = *(const f32x4*)&Mf[(kt * 16 + c) * 36 + s * 16 + quad * 4];
                sc[s][kt] = MFMA16(qf[s], kf, c0);
            }
        }
        bf16x8 vf = *(const bf16x8*)&Vtt[(hh * 16 + c) * 36 + quad * 8];

        // softmax: p = exp2(s + madd); masked entries give exactly 0
#pragma unroll
        for (int s = 0; s < 2; ++s) {
#pragma unroll
            for (int r = 0; r < 4; ++r) {
                float e0 = exp2f(sc[s][0][r]);   // key c      -> slot 2c lo
                float e1 = exp2f(sc[s][1][r]);   // key 16+c   -> slot 2c hi
                ls[s][r] += e0 + e1;
                int row = s * 16 + quad * 4 + r;
                *(u32*)&Ps[hh][row * 36 + 2 * c] = packbf2(e0, e1);
            }
        }

        // PV in permuted key order (matches Vtt slot order)
#pragma unroll
        for (int s = 0; s < 2; ++s) {
            bf16x8 pf = *(const bf16x8*)&Ps[hh][(s * 16 + c) * 36 + quad * 8];
            O[s] = MFMA16(pf, vf, O[s]);
        }
    }

    // l-reduction and heads -> LDS (reuse Kt as Hs, stride 136)
    float rl[2][4];
#pragma unroll
    for (int s = 0; s < 2; ++s)
#pragma unroll
        for (int r = 0; r < 4; ++r) {
            float l = ls[s][r];
            l += __shfl_xor(l, 1);
            l += __shfl_xor(l, 2);
            l += __shfl_xor(l, 4);
            l += __shfl_xor(l, 8);
            rl[s][r] = (l > 0.f) ? 1.f / l : 0.f;
        }
    __syncthreads();   // all Kt reads of last iter done
    u16* Hs = Kt;
#pragma unroll
    for (int s = 0; s < 2; ++s)
#pragma unroll
        for (int r = 0; r < 4; ++r)
            Hs[(s * 16 + quad * 4 + r) * 136 + hh * 16 + c] = f2bf(O[s][r] * rl[s][r]);
    __syncthreads();

    // fused out-projection: wave hh computes out cols hh*16..+15
    f32x4 oacc[2] = {zf, zf};
#pragma unroll
    for (int kt = 0; kt < 4; ++kt) {
        bf16x8 bfr = *(const bf16x8*)&Wob[(hh * 16 + c) * 128 + kt * 32 + quad * 8];
#pragma unroll
        for (int s = 0; s < 2; ++s) {
            bf16x8 af = *(const bf16x8*)&Hs[(s * 16 + c) * 136 + kt * 32 + quad * 8];
            oacc[s] = MFMA16(af, bfr, oacc[s]);
        }
    }
#pragma unroll
    for (int s = 0; s < 2; ++s)
#pragma unroll
        for (int r = 0; r < 4; ++r)
            out[((size_t)b * NQ + q0 + s * 16 + quad * 4 + r) * 128 + hh * 16 + c] =
                oacc[s][r];
}

extern "C" void kernel_launch(void* const* d_in, const int* in_sizes, int n_in,
                              void* d_out, int out_size, void* d_ws, size_t ws_size,
                              hipStream_t stream) {
    const float* q    = (const float*)d_in[0];
    const float* h    = (const float*)d_in[1];
    const int*   mask = (const int*)d_in[2];
    const float* Wq   = (const float*)d_in[3];
    const float* Wk   = (const float*)d_in[4];
    const float* Wv   = (const float*)d_in[5];
    const float* Wout = (const float*)d_in[6];
    float* out = (float*)d_out;

    const size_t NTOK = (size_t)NB * NQ;     // 32768
    u16* Qb  = (u16*)d_ws;                   // 8 MB each
    u16* Kb  = Qb + NTOK * 128;
    u16* Vtg = Kb + NTOK * 128;              // V transposed: [b][dim][token]
    u16* Wob = Vtg + NTOK * 128;             // Wout prepped [d][16h+e], 32 KB

    proj_mfma<<<dim3(256, 3), 256, 0, stream>>>(q, h, Wq, Wk, Wv, Wout,
                                                Qb, Kb, Vtg, Wob);
    flash_mfma<<<dim3(NB, NQ / 32), 512, 0, stream>>>(Qb, Kb, Vtg, mask, Wob, out);
}

// Round 7
// 316.636 us; speedup vs baseline: 9.1940x; 1.0194x over previous
//
#include <hip/hip_runtime.h>

typedef unsigned short u16;
typedef unsigned int   u32;
typedef short bf16x8 __attribute__((ext_vector_type(8)));
typedef float f32x4  __attribute__((ext_vector_type(4)));

#define NB  32
#define NQ  1024
#define GS  1024
#define NH  8
#define SCQ (0.25f * 1.4426950408889634f)   /* 1/sqrt(16) * log2(e) */
#define MBIG (-1.0e30f)

#define MFMA16(a, b, c) __builtin_amdgcn_mfma_f32_16x16x32_bf16(a, b, c, 0, 0, 0)

__device__ __forceinline__ u16 f2bf(float f) {  // RNE float->bf16 bits
    u32 u = __float_as_uint(f);
    return (u16)((u + 0x7fffu + ((u >> 16) & 1u)) >> 16);
}
__device__ __forceinline__ u32 pk2bf(float a, float b) {  // 2x round-half-up, packed
    u32 ua = (__float_as_uint(a) + 0x8000u) >> 16;
    u32 ub = (__float_as_uint(b) + 0x8000u) & 0xffff0000u;
    return ua | ub;
}

// ---------------------------------------------------------------------------
// Weight prep (32 blocks): Wp[m][i] bf16.
//  m=0..2 (Wq/Wk/Wv [8][128][16]): i = col*128 + k, col=16h+e, k=d; SCQ in m=0.
//  m=3 (Wout [8][16][128]):        i = d*128 + he   (Wob layout for fused out).
// ---------------------------------------------------------------------------
__global__ __launch_bounds__(256) void wprep(const float* __restrict__ Wq,
                                             const float* __restrict__ Wk,
                                             const float* __restrict__ Wv,
                                             const float* __restrict__ Wout,
                                             u16* __restrict__ Wp) {
    int m  = blockIdx.x >> 3;
    int sl = blockIdx.x & 7;
    const float* src = (m == 0) ? Wq : (m == 1) ? Wk : (m == 2) ? Wv : Wout;
    float sc = (m == 0) ? SCQ : 1.0f;
    for (int i = sl * 2048 + threadIdx.x; i < (sl + 1) * 2048; i += 256) {
        float v;
        if (m < 3) { int cc = i >> 7, k = i & 127;  v = src[(cc >> 4) * 2048 + k * 16 + (cc & 15)]; }
        else       { int d  = i >> 7, he = i & 127; v = src[(he >> 4) * 2048 + (he & 15) * 128 + d]; }
        Wp[m * 16384 + i] = f2bf(v * sc);
    }
}

// ---------------------------------------------------------------------------
// MFMA GEMM: C[128x128] = A[128x128] * W^T, K=128 staged once.
// 256 thr = 4 waves; A fp32 -> bf16 in staging; W prepped bf16 (b128 copies).
// MODE 0: bf16 out row-major; MODE 2: bf16 out transposed (Vt_g[b][col][tok]).
// ---------------------------------------------------------------------------
template <int MODE>
__device__ __forceinline__ void mgemm(const float* __restrict__ Ain,
                                      const u16* __restrict__ Wpm,
                                      u16* __restrict__ outb,
                                      u16* As, u16* Ws, int row0) {
    const int t    = threadIdx.x;
    const int wv   = t >> 6;
    const int lane = t & 63;
    const int quad = lane >> 4;
    const int c    = lane & 15;

#pragma unroll
    for (int g0 = 0; g0 < 2048; g0 += 256) {
        int g = g0 + t;
        int row = g >> 4, k0 = (g & 15) * 8;
        const float4* ap = (const float4*)&Ain[(size_t)(row0 + row) * 128 + k0];
        float4 a0 = ap[0], a1 = ap[1];
        int4 pk;
        pk.x = (int)pk2bf(a0.x, a0.y);
        pk.y = (int)pk2bf(a0.z, a0.w);
        pk.z = (int)pk2bf(a1.x, a1.y);
        pk.w = (int)pk2bf(a1.z, a1.w);
        *(int4*)&As[row * 136 + k0] = pk;
    }
#pragma unroll
    for (int g0 = 0; g0 < 2048; g0 += 256) {
        int g = g0 + t;
        int cc = g >> 4, k0 = (g & 15) * 8;
        *(int4*)&Ws[cc * 136 + k0] = *(const int4*)&Wpm[cc * 128 + k0];
    }
    __syncthreads();

    const f32x4 zf = {0.f, 0.f, 0.f, 0.f};
    f32x4 acc[2][8];
#pragma unroll
    for (int s = 0; s < 2; ++s)
#pragma unroll
        for (int j = 0; j < 8; ++j) acc[s][j] = zf;

#pragma unroll
    for (int kt = 0; kt < 4; ++kt) {
        bf16x8 af0 = *(const bf16x8*)&As[(wv * 32 + c) * 136 + kt * 32 + quad * 8];
        bf16x8 af1 = *(const bf16x8*)&As[(wv * 32 + 16 + c) * 136 + kt * 32 + quad * 8];
#pragma unroll
        for (int j = 0; j < 8; ++j) {
            bf16x8 bfr = *(const bf16x8*)&Ws[(j * 16 + c) * 136 + kt * 32 + quad * 8];
            acc[0][j] = MFMA16(af0, bfr, acc[0][j]);
            acc[1][j] = MFMA16(af1, bfr, acc[1][j]);
        }
    }

#pragma unroll
    for (int s = 0; s < 2; ++s)
#pragma unroll
        for (int j = 0; j < 8; ++j)
#pragma unroll
            for (int r = 0; r < 4; ++r) {
                int row = row0 + wv * 32 + s * 16 + quad * 4 + r;
                int col = j * 16 + c;
                float v = acc[s][j][r];
                if (MODE == 0) {
                    outb[(size_t)row * 128 + col] = f2bf(v);
                } else {
                    int bI = row >> 10, tb = row & 1023;
                    outb[(size_t)bI * (128 * 1024) + (size_t)col * 1024 + tb] = f2bf(v);
                }
            }
}

__global__ __launch_bounds__(256, 2) void proj_mfma(const float* __restrict__ q,
                                                    const float* __restrict__ h,
                                                    const u16* __restrict__ Wp,
                                                    u16* __restrict__ Qb,
                                                    u16* __restrict__ Kb,
                                                    u16* __restrict__ Vtg) {
    __shared__ u16 As[128 * 136];
    __shared__ u16 Ws[128 * 136];
    int row0 = blockIdx.x * 128;
    if (blockIdx.y == 0)      mgemm<0>(q, Wp,         Qb,  As, Ws, row0);
    else if (blockIdx.y == 1) mgemm<0>(h, Wp + 16384, Kb,  As, Ws, row0);
    else                      mgemm<2>(h, Wp + 32768, Vtg, As, Ws, row0);
}

// ---------------------------------------------------------------------------
// MFMA flash attention + fused out-projection.
// Block = (batch, 32 q-rows), 512 thr = 8 waves = 8 heads.
// Mask folded into score-MFMA C operand via Mf[key][row'] floats {0,-1e30},
// row' = r | (s<<2) | ((q>>1)<<3) | ((q&1)<<4)  -> b128-aligned C-frag reads
// at dword banks 4c+8(q>>1)+16(q&1): 4-way max (was 8-way in R6).
// P packed 2 keys/u32 interleaved; V staged in the same key order.
// Epilogue: heads -> LDS (reuses Kt) -> 8 MFMAs/wave vs Wob -> fp32 out.
// LDS: 8704+9216+18432+4608 = 40960 B exactly -> 4 blocks/CU.
// ---------------------------------------------------------------------------
__global__ __launch_bounds__(512, 4) void flash_mfma(const u16* __restrict__ Qb,
                                                     const u16* __restrict__ Kb,
                                                     const u16* __restrict__ Vtg,
                                                     const int* __restrict__ mask,
                                                     const u16* __restrict__ Wob,
                                                     float* __restrict__ out) {
    __shared__ u16 Kt[32 * 136];        // [key][dim]; reused as Hs after loop
    __shared__ u16 Vtt[128 * 36];       // [dim][key-slot]
    __shared__ u16 Ps[NH][32 * 36];     // per-wave P [row][key-slot]
    __shared__ float Mf[32 * 36];       // mask addend [key][row'], stride 36

    const int b    = blockIdx.x;
    const int q0   = blockIdx.y * 32;
    const int t    = threadIdx.x;
    const int hh   = t >> 6;
    const int lane = t & 63;
    const int quad = lane >> 4;
    const int c    = lane & 15;

    const f32x4  zf = {0.f, 0.f, 0.f, 0.f};
    const bf16x8 zb = {0, 0, 0, 0, 0, 0, 0, 0};

    bf16x8 qf[2];
#pragma unroll
    for (int s = 0; s < 2; ++s) {
        qf[s] = zb;
        if (quad < 2)
            qf[s] = *(const bf16x8*)&Qb[((size_t)b * NQ + q0 + s * 16 + c) * 128 +
                                        hh * 16 + quad * 8];
    }

    f32x4 O[2] = {zf, zf};
    float ls[2][4] = {{0.f, 0.f, 0.f, 0.f}, {0.f, 0.f, 0.f, 0.f}};

    // staging indices
    const int skey = t >> 4;            // K: key 0..31, dim octet (t&15)*8
    const int sd0  = (t & 15) * 8;
    const int vdim = t >> 2;            // V: dim 0..127, token quad vq
    const int vq   = t & 3;
    const int mrow = t >> 4;            // M: row 0..31, key pair (t&15)*2
    const int mk0  = (t & 15) * 2;
    // permuted row index for Mf (see header comment)
    const int rp = (mrow & 3) | (((mrow >> 4) & 1) << 2) |
                   (((mrow >> 3) & 1) << 3) | (((mrow >> 2) & 1) << 4);

    const u16* Kbase = &Kb[((size_t)b * GS + skey) * 128 + sd0];
    const u16* Vbase = &Vtg[(size_t)b * (128 * 1024) + (size_t)vdim * 1024];
    const int* Mbase = &mask[((size_t)b * NQ + q0 + mrow) * GS + mk0];

    int4 kreg = *(const int4*)Kbase;
    int2 va   = *(const int2*)(Vbase + vq * 4);
    int2 vb   = *(const int2*)(Vbase + 16 + vq * 4);
    int2 mreg = *(const int2*)Mbase;

    // Mf read offset within a row-column: r low bits; quad bits at 8/16
    const int mfoff = ((quad >> 1) << 3) | ((quad & 1) << 4);

    for (int g0 = 0; g0 < GS; g0 += 32) {
        __syncthreads();
        *(int4*)&Kt[skey * 136 + sd0] = kreg;
        {   // interleave: slot 2k = key k, slot 2k+1 = key 16+k (k = 4vq+i)
            int4 w;
            w.x = (int)(((u32)va.x & 0xffffu) | ((u32)vb.x << 16));
            w.y = (int)(((u32)va.x >> 16) | ((u32)vb.x & 0xffff0000u));
            w.z = (int)(((u32)va.y & 0xffffu) | ((u32)vb.y << 16));
            w.w = (int)(((u32)va.y >> 16) | ((u32)vb.y & 0xffff0000u));
            *(int4*)&Vtt[vdim * 36 + vq * 8] = w;
        }
        Mf[mk0 * 36 + rp]       = mreg.x ? MBIG : 0.f;
        Mf[(mk0 + 1) * 36 + rp] = mreg.y ? MBIG : 0.f;
        __syncthreads();

        if (g0 + 32 < GS) {
            kreg = *(const int4*)(Kbase + (size_t)(g0 + 32) * 128);
            va   = *(const int2*)(Vbase + g0 + 32 + vq * 4);
            vb   = *(const int2*)(Vbase + g0 + 48 + vq * 4);
            mreg = *(const int2*)(Mbase + (g0 + 32));
        }

        // scores with mask addend pre-loaded into C
        f32x4 sc[2][2];
#pragma unroll
        for (int kt = 0; kt < 2; ++kt) {
            bf16x8 kf = zb;
            if (quad < 2)
                kf = *(const bf16x8*)&Kt[(kt * 16 + c) * 136 + hh * 16 + quad * 8];
#pragma unroll
            for (int s = 0; s < 2; ++s) {
                f32x4 c0 = *(const f32x4*)&Mf[(kt * 16 + c) * 36 + (s << 2) + mfoff];
                sc[s][kt] = MFMA16(qf[s], kf, c0);
            }
        }
        bf16x8 vf = *(const bf16x8*)&Vtt[(hh * 16 + c) * 36 + quad * 8];

        // softmax: p = exp2(s + madd); masked -> exactly 0
#pragma unroll
        for (int s = 0; s < 2; ++s) {
#pragma unroll
            for (int r = 0; r < 4; ++r) {
                float e0 = exp2f(sc[s][0][r]);   // key c    -> slot 2c lo
                float e1 = exp2f(sc[s][1][r]);   // key 16+c -> slot 2c hi
                ls[s][r] += e0 + e1;
                int row = s * 16 + quad * 4 + r;
                *(u32*)&Ps[hh][row * 36 + 2 * c] = pk2bf(e0, e1);
            }
        }

        // PV in permuted key order (matches Vtt slots)
#pragma unroll
        for (int s = 0; s < 2; ++s) {
            bf16x8 pf = *(const bf16x8*)&Ps[hh][(s * 16 + c) * 36 + quad * 8];
            O[s] = MFMA16(pf, vf, O[s]);
        }
    }

    // l-reduction, heads -> LDS (reuse Kt as Hs, stride 136)
    float rl[2][4];
#pragma unroll
    for (int s = 0; s < 2; ++s)
#pragma unroll
        for (int r = 0; r < 4; ++r) {
            float l = ls[s][r];
            l += __shfl_xor(l, 1);
            l += __shfl_xor(l, 2);
            l += __shfl_xor(l, 4);
            l += __shfl_xor(l, 8);
            rl[s][r] = (l > 0.f) ? 1.f / l : 0.f;
        }
    __syncthreads();
    u16* Hs = Kt;
#pragma unroll
    for (int s = 0; s < 2; ++s)
#pragma unroll
        for (int r = 0; r < 4; ++r)
            Hs[(s * 16 + quad * 4 + r) * 136 + hh * 16 + c] = f2bf(O[s][r] * rl[s][r]);
    __syncthreads();

    // fused out-projection: wave hh computes out cols hh*16..+15
    f32x4 oacc[2] = {zf, zf};
#pragma unroll
    for (int kt = 0; kt < 4; ++kt) {
        bf16x8 bfr = *(const bf16x8*)&Wob[(hh * 16 + c) * 128 + kt * 32 + quad * 8];
#pragma unroll
        for (int s = 0; s < 2; ++s) {
            bf16x8 af = *(const bf16x8*)&Hs[(s * 16 + c) * 136 + kt * 32 + quad * 8];
            oacc[s] = MFMA16(af, bfr, oacc[s]);
        }
    }
#pragma unroll
    for (int s = 0; s < 2; ++s)
#pragma unroll
        for (int r = 0; r < 4; ++r)
            out[((size_t)b * NQ + q0 + s * 16 + quad * 4 + r) * 128 + hh * 16 + c] =
                oacc[s][r];
}

extern "C" void kernel_launch(void* const* d_in, const int* in_sizes, int n_in,
                              void* d_out, int out_size, void* d_ws, size_t ws_size,
                              hipStream_t stream) {
    const float* q    = (const float*)d_in[0];
    const float* h    = (const float*)d_in[1];
    const int*   mask = (const int*)d_in[2];
    const float* Wq   = (const float*)d_in[3];
    const float* Wk   = (const float*)d_in[4];
    const float* Wv   = (const float*)d_in[5];
    const float* Wout = (const float*)d_in[6];
    float* out = (float*)d_out;

    const size_t NTOK = (size_t)NB * NQ;     // 32768
    u16* Qb  = (u16*)d_ws;                   // 8 MB each
    u16* Kb  = Qb + NTOK * 128;
    u16* Vtg = Kb + NTOK * 128;              // V transposed: [b][dim][token]
    u16* Wp  = Vtg + NTOK * 128;             // prepped weights (incl. Wob), 128 KB

    wprep<<<dim3(32), 256, 0, stream>>>(Wq, Wk, Wv, Wout, Wp);
    proj_mfma<<<dim3(256, 3), 256, 0, stream>>>(q, h, Wp, Qb, Kb, Vtg);
    flash_mfma<<<dim3(NB, NQ / 32), 512, 0, stream>>>(Qb, Kb, Vtg, mask,
                                                      Wp + 49152, out);
}

// Round 9
// 313.211 us; speedup vs baseline: 9.2946x; 1.0109x over previous
//
#include <hip/hip_runtime.h>

typedef unsigned short u16;
typedef unsigned int   u32;
typedef short bf16x8 __attribute__((ext_vector_type(8)));
typedef float f32x4  __attribute__((ext_vector_type(4)));

#define NB  32
#define NQ  1024
#define GS  1024
#define NH  8
#define SCQ (0.25f * 1.4426950408889634f)   /* 1/sqrt(16) * log2(e) */
#define MBIG (-1.0e30f)

#define MFMA16(a, b, c) __builtin_amdgcn_mfma_f32_16x16x32_bf16(a, b, c, 0, 0, 0)

__device__ __forceinline__ u16 f2bf(float f) {  // RNE float->bf16 bits
    u32 u = __float_as_uint(f);
    return (u16)((u + 0x7fffu + ((u >> 16) & 1u)) >> 16);
}
// packed round-half-up: result = bf(a) | bf(b)<<16, 3 VALU ops via v_perm_b32
__device__ __forceinline__ u32 pk2bf(float a, float b) {
    u32 ua = __float_as_uint(a) + 0x8000u;
    u32 ub = __float_as_uint(b) + 0x8000u;
    return __builtin_amdgcn_perm(ub, ua, 0x07060302u);  // bytes [b3 b2 a3 a2]
}

// ---------------------------------------------------------------------------
// Weight prep (32 blocks): Wp[m][i] bf16.
//  m=0..2 (Wq/Wk/Wv [8][128][16]): i = col*128 + k, col=16h+e, k=d; SCQ in m=0.
//  m=3 (Wout [8][16][128]):        i = d*128 + he   (Wob layout for fused out).
// ---------------------------------------------------------------------------
__global__ __launch_bounds__(256) void wprep(const float* __restrict__ Wq,
                                             const float* __restrict__ Wk,
                                             const float* __restrict__ Wv,
                                             const float* __restrict__ Wout,
                                             u16* __restrict__ Wp) {
    int m  = blockIdx.x >> 3;
    int sl = blockIdx.x & 7;
    const float* src = (m == 0) ? Wq : (m == 1) ? Wk : (m == 2) ? Wv : Wout;
    float sc = (m == 0) ? SCQ : 1.0f;
    for (int i = sl * 2048 + threadIdx.x; i < (sl + 1) * 2048; i += 256) {
        float v;
        if (m < 3) { int cc = i >> 7, k = i & 127;  v = src[(cc >> 4) * 2048 + k * 16 + (cc & 15)]; }
        else       { int d  = i >> 7, he = i & 127; v = src[(he >> 4) * 2048 + (he & 15) * 128 + d]; }
        Wp[m * 16384 + i] = f2bf(v * sc);
    }
}

// ---------------------------------------------------------------------------
// MFMA GEMM: C[128x128] = A[128x128] * W^T, K=128 staged once.
// 256 thr = 4 waves; A fp32 -> bf16 in staging; W prepped bf16 (b128 copies).
// MODE 0: bf16 out row-major.
// MODE 2: bf16 out transposed per batch with PERMUTED token slots:
//         Vt_g[b][col][tb'] , tb' = (tb&~31) | 2*(tb&15) | ((tb>>4)&1)
//         (matches flash's interleaved PV key order -> flash stages V by copy)
// ---------------------------------------------------------------------------
template <int MODE>
__device__ __forceinline__ void mgemm(const float* __restrict__ Ain,
                                      const u16* __restrict__ Wpm,
                                      u16* __restrict__ outb,
                                      u16* As, u16* Ws, int row0) {
    const int t    = threadIdx.x;
    const int wv   = t >> 6;
    const int lane = t & 63;
    const int quad = lane >> 4;
    const int c    = lane & 15;

#pragma unroll
    for (int g0 = 0; g0 < 2048; g0 += 256) {
        int g = g0 + t;
        int row = g >> 4, k0 = (g & 15) * 8;
        const float4* ap = (const float4*)&Ain[(size_t)(row0 + row) * 128 + k0];
        float4 a0 = ap[0], a1 = ap[1];
        int4 pk;
        pk.x = (int)pk2bf(a0.x, a0.y);
        pk.y = (int)pk2bf(a0.z, a0.w);
        pk.z = (int)pk2bf(a1.x, a1.y);
        pk.w = (int)pk2bf(a1.z, a1.w);
        *(int4*)&As[row * 136 + k0] = pk;
    }
#pragma unroll
    for (int g0 = 0; g0 < 2048; g0 += 256) {
        int g = g0 + t;
        int cc = g >> 4, k0 = (g & 15) * 8;
        *(int4*)&Ws[cc * 136 + k0] = *(const int4*)&Wpm[cc * 128 + k0];
    }
    __syncthreads();

    const f32x4 zf = {0.f, 0.f, 0.f, 0.f};
    f32x4 acc[2][8];
#pragma unroll
    for (int s = 0; s < 2; ++s)
#pragma unroll
        for (int j = 0; j < 8; ++j) acc[s][j] = zf;

#pragma unroll
    for (int kt = 0; kt < 4; ++kt) {
        bf16x8 af0 = *(const bf16x8*)&As[(wv * 32 + c) * 136 + kt * 32 + quad * 8];
        bf16x8 af1 = *(const bf16x8*)&As[(wv * 32 + 16 + c) * 136 + kt * 32 + quad * 8];
#pragma unroll
        for (int j = 0; j < 8; ++j) {
            bf16x8 bfr = *(const bf16x8*)&Ws[(j * 16 + c) * 136 + kt * 32 + quad * 8];
            acc[0][j] = MFMA16(af0, bfr, acc[0][j]);
            acc[1][j] = MFMA16(af1, bfr, acc[1][j]);
        }
    }

#pragma unroll
    for (int s = 0; s < 2; ++s)
#pragma unroll
        for (int j = 0; j < 8; ++j)
#pragma unroll
            for (int r = 0; r < 4; ++r) {
                int row = row0 + wv * 32 + s * 16 + quad * 4 + r;
                int col = j * 16 + c;
                float v = acc[s][j][r];
                if (MODE == 0) {
                    outb[(size_t)row * 128 + col] = f2bf(v);
                } else {
                    int bI = row >> 10, tb = row & 1023;
                    int tbp = (tb & ~31) | (2 * (tb & 15)) | ((tb >> 4) & 1);
                    outb[(size_t)bI * (128 * 1024) + (size_t)col * 1024 + tbp] = f2bf(v);
                }
            }
}

__global__ __launch_bounds__(256, 2) void proj_mfma(const float* __restrict__ q,
                                                    const float* __restrict__ h,
                                                    const u16* __restrict__ Wp,
                                                    u16* __restrict__ Qb,
                                                    u16* __restrict__ Kb,
                                                    u16* __restrict__ Vtg) {
    __shared__ u16 As[128 * 136];
    __shared__ u16 Ws[128 * 136];
    int row0 = blockIdx.x * 128;
    if (blockIdx.y == 0)      mgemm<0>(q, Wp,         Qb,  As, Ws, row0);
    else if (blockIdx.y == 1) mgemm<0>(h, Wp + 16384, Kb,  As, Ws, row0);
    else                      mgemm<2>(h, Wp + 32768, Vtg, As, Ws, row0);
}

// ---------------------------------------------------------------------------
// MFMA flash attention + fused out-projection.
// Block = (batch, 32 q-rows), 512 thr = 8 waves = 8 heads.
// Mask folded into score-MFMA C operand (Mf floats {0,-1e30}).
// V arrives globally pre-permuted -> staging is a straight int4 copy.
// kf read unconditional: safe because Kt pad columns [128,136) are ZEROED
// once at kernel start (uninitialized LDS can hold NaN patterns and
// MFMA 0*NaN = NaN — the R8 bug). qf zeros kill the padded products.
// LDS: 8704+9216+18432+4608 = 40960 B exactly -> 4 blocks/CU.
// ---------------------------------------------------------------------------
__global__ __launch_bounds__(512, 4) void flash_mfma(const u16* __restrict__ Qb,
                                                     const u16* __restrict__ Kb,
                                                     const u16* __restrict__ Vtg,
                                                     const int* __restrict__ mask,
                                                     const u16* __restrict__ Wob,
                                                     float* __restrict__ out) {
    __shared__ u16 Kt[32 * 136];        // [key][dim]; reused as Hs after loop
    __shared__ u16 Vtt[128 * 36];       // [dim][key-slot]
    __shared__ u16 Ps[NH][32 * 36];     // per-wave P [row][key-slot]
    __shared__ float Mf[32 * 36];       // mask addend [key][row'], stride 36

    const int b    = blockIdx.x;
    const int q0   = blockIdx.y * 32;
    const int t    = threadIdx.x;
    const int hh   = t >> 6;
    const int lane = t & 63;
    const int quad = lane >> 4;
    const int c    = lane & 15;

    // zero Kt pad columns [128,136) of all 32 rows (one-time; see header)
    if (t < 128)
        *(u32*)&Kt[(t >> 2) * 136 + 128 + (t & 3) * 2] = 0u;

    const f32x4  zf = {0.f, 0.f, 0.f, 0.f};
    const bf16x8 zb = {0, 0, 0, 0, 0, 0, 0, 0};

    bf16x8 qf[2];
#pragma unroll
    for (int s = 0; s < 2; ++s) {
        qf[s] = zb;
        if (quad < 2)
            qf[s] = *(const bf16x8*)&Qb[((size_t)b * NQ + q0 + s * 16 + c) * 128 +
                                        hh * 16 + quad * 8];
    }

    f32x4 O[2] = {zf, zf};
    float ls[2][4] = {{0.f, 0.f, 0.f, 0.f}, {0.f, 0.f, 0.f, 0.f}};

    // staging indices
    const int skey = t >> 4;            // K: key 0..31, dim octet (t&15)*8
    const int sd0  = (t & 15) * 8;
    const int vdim = t >> 2;            // V: dim 0..127, slot octet (t&3)*8
    const int vs0  = (t & 3) * 8;
    const int mrow = t >> 4;            // M: row 0..31, key pair (t&15)*2
    const int mk0  = (t & 15) * 2;
    const int rp = (mrow & 3) | (((mrow >> 4) & 1) << 2) |
                   (((mrow >> 3) & 1) << 3) | (((mrow >> 2) & 1) << 4);

    const u16* Kptr = &Kb[((size_t)b * GS + skey) * 128 + sd0];
    const u16* Vptr = &Vtg[(size_t)b * (128 * 1024) + (size_t)vdim * 1024 + vs0];
    const int* Mptr = &mask[((size_t)b * NQ + q0 + mrow) * GS + mk0];

    int4 kreg = *(const int4*)Kptr;
    int4 vreg = *(const int4*)Vptr;
    int2 mreg = *(const int2*)Mptr;

    const int mfoff = ((quad >> 1) << 3) | ((quad & 1) << 4);

    for (int g0 = 0; g0 < GS; g0 += 32) {
        __syncthreads();
        *(int4*)&Kt[skey * 136 + sd0] = kreg;
        *(int4*)&Vtt[vdim * 36 + vs0] = vreg;
        Mf[mk0 * 36 + rp]       = mreg.x ? MBIG : 0.f;
        Mf[(mk0 + 1) * 36 + rp] = mreg.y ? MBIG : 0.f;
        __syncthreads();

        if (g0 + 32 < GS) {
            Kptr += 32 * 128;  kreg = *(const int4*)Kptr;
            Vptr += 32;        vreg = *(const int4*)Vptr;
            Mptr += 32;        mreg = *(const int2*)Mptr;
        }

        // scores with mask addend pre-loaded into C
        f32x4 sc[2][2];
#pragma unroll
        for (int kt = 0; kt < 2; ++kt) {
            bf16x8 kf = *(const bf16x8*)&Kt[(kt * 16 + c) * 136 + hh * 16 + quad * 8];
#pragma unroll
            for (int s = 0; s < 2; ++s) {
                f32x4 c0 = *(const f32x4*)&Mf[(kt * 16 + c) * 36 + (s << 2) + mfoff];
                sc[s][kt] = MFMA16(qf[s], kf, c0);
            }
        }
        bf16x8 vf = *(const bf16x8*)&Vtt[(hh * 16 + c) * 36 + quad * 8];

        // softmax: p = exp2(s + madd); masked -> exactly 0
#pragma unroll
        for (int s = 0; s < 2; ++s) {
#pragma unroll
            for (int r = 0; r < 4; ++r) {
                float e0 = exp2f(sc[s][0][r]);   // key c    -> slot 2c lo
                float e1 = exp2f(sc[s][1][r]);   // key 16+c -> slot 2c hi
                ls[s][r] += e0 + e1;
                int row = s * 16 + quad * 4 + r;
                *(u32*)&Ps[hh][row * 36 + 2 * c] = pk2bf(e0, e1);
            }
        }

        // PV in permuted key order (matches Vtt slots)
#pragma unroll
        for (int s = 0; s < 2; ++s) {
            bf16x8 pf = *(const bf16x8*)&Ps[hh][(s * 16 + c) * 36 + quad * 8];
            O[s] = MFMA16(pf, vf, O[s]);
        }
    }

    // l-reduction, heads -> LDS (reuse Kt as Hs, stride 136)
    float rl[2][4];
#pragma unroll
    for (int s = 0; s < 2; ++s)
#pragma unroll
        for (int r = 0; r < 4; ++r) {
            float l = ls[s][r];
            l += __shfl_xor(l, 1);
            l += __shfl_xor(l, 2);
            l += __shfl_xor(l, 4);
            l += __shfl_xor(l, 8);
            rl[s][r] = (l > 0.f) ? 1.f / l : 0.f;
        }
    __syncthreads();
    u16* Hs = Kt;
#pragma unroll
    for (int s = 0; s < 2; ++s)
#pragma unroll
        for (int r = 0; r < 4; ++r)
            Hs[(s * 16 + quad * 4 + r) * 136 + hh * 16 + c] = f2bf(O[s][r] * rl[s][r]);
    __syncthreads();

    // fused out-projection: wave hh computes out cols hh*16..+15
    f32x4 oacc[2] = {zf, zf};
#pragma unroll
    for (int kt = 0; kt < 4; ++kt) {
        bf16x8 bfr = *(const bf16x8*)&Wob[(hh * 16 + c) * 128 + kt * 32 + quad * 8];
#pragma unroll
        for (int s = 0; s < 2; ++s) {
            bf16x8 af = *(const bf16x8*)&Hs[(s * 16 + c) * 136 + kt * 32 + quad * 8];
            oacc[s] = MFMA16(af, bfr, oacc[s]);
        }
    }
#pragma unroll
    for (int s = 0; s < 2; ++s)
#pragma unroll
        for (int r = 0; r < 4; ++r)
            out[((size_t)b * NQ + q0 + s * 16 + quad * 4 + r) * 128 + hh * 16 + c] =
                oacc[s][r];
}

extern "C" void kernel_launch(void* const* d_in, const int* in_sizes, int n_in,
                              void* d_out, int out_size, void* d_ws, size_t ws_size,
                              hipStream_t stream) {
    const float* q    = (const float*)d_in[0];
    const float* h    = (const float*)d_in[1];
    const int*   mask = (const int*)d_in[2];
    const float* Wq   = (const float*)d_in[3];
    const float* Wk   = (const float*)d_in[4];
    const float* Wv   = (const float*)d_in[5];
    const float* Wout = (const float*)d_in[6];
    float* out = (float*)d_out;

    const size_t NTOK = (size_t)NB * NQ;     // 32768
    u16* Qb  = (u16*)d_ws;                   // 8 MB each
    u16* Kb  = Qb + NTOK * 128;
    u16* Vtg = Kb + NTOK * 128;              // V transposed+permuted per batch
    u16* Wp  = Vtg + NTOK * 128;             // prepped weights (incl. Wob), 128 KB

    wprep<<<dim3(32), 256, 0, stream>>>(Wq, Wk, Wv, Wout, Wp);
    proj_mfma<<<dim3(256, 3), 256, 0, stream>>>(q, h, Wp, Qb, Kb, Vtg);
    flash_mfma<<<dim3(NB, NQ / 32), 512, 0, stream>>>(Qb, Kb, Vtg, mask,
                                                      Wp + 49152, out);
}